// Round 2
// baseline (3330.051 us; speedup 1.0000x reference)
//
#include <hip/hip_runtime.h>
#include <math.h>

#define H 16
#define S 2048
#define D 64
#define SCALEQK 0.125f
#define CH 256

typedef __attribute__((ext_vector_type(4))) float f32x4;
typedef __attribute__((ext_vector_type(8))) short bf16x8;

// split f32 -> bf16 hi + bf16 lo (residual), rne; packed into two uint4 (8 elems)
__device__ inline void stage_hilo(float4 a, float4 b, uint4* vh, uint4* vl) {
    float xs[8] = {a.x, a.y, a.z, a.w, b.x, b.y, b.z, b.w};
    unsigned int hh[8], ll[8];
#pragma unroll
    for (int j = 0; j < 8; ++j) {
        unsigned int u = __float_as_uint(xs[j]);
        unsigned int h = (u + 0x7fffu + ((u >> 16) & 1u)) >> 16;
        float r = xs[j] - __uint_as_float(h << 16);
        unsigned int u2 = __float_as_uint(r);
        hh[j] = h;
        ll[j] = (u2 + 0x7fffu + ((u2 >> 16) & 1u)) >> 16;
    }
    uint4 h4, l4;
    h4.x = hh[0] | (hh[1] << 16); h4.y = hh[2] | (hh[3] << 16);
    h4.z = hh[4] | (hh[5] << 16); h4.w = hh[6] | (hh[7] << 16);
    l4.x = ll[0] | (ll[1] << 16); l4.y = ll[2] | (ll[3] << 16);
    l4.z = ll[4] | (ll[5] << 16); l4.w = ll[6] | (ll[7] << 16);
    *vh = h4; *vl = l4;
}

__device__ inline void online_upd(float& m, float& l, float x) {
    if (x > m) { l = l * __expf(m - x) + 1.f; m = x; }
    else       { l += __expf(x - m); }
}

// Pass 1: mixed scores (QK^T split-bf16 MFMA + 6x11 causal conv + w_psm mix) -> online (m,l)
// block: 16 q rows x 256-k chunk; all 16 heads.
__global__ __launch_bounds__(256) void mta_stats_kernel(
        const float* __restrict__ xq, const float* __restrict__ xk,
        const float* __restrict__ w_pre, const float* __restrict__ w_psm,
        float* __restrict__ mpart, float* __restrict__ lpart) {
    const int kc = blockIdx.x, qt = blockIdx.y;
    const int q0 = qt * 16;
    const int kstart = kc * CH;
    if (kstart > q0 + 15) return;
    const int kend = min(kstart + CH, q0 + 16);
    const int tid = threadIdx.x;

    __shared__ unsigned short Qs[2][32][72];  // rows q0-5..q0+26 (21 valid)
    __shared__ unsigned short Ks[2][48][72];  // rows k0-10..k0+37 (42 valid)
    __shared__ float raws[32][50];
    __shared__ float wpre_s[16 * 66];
    __shared__ float wpsm_s[256];

    for (int i = tid; i < 16 * 66; i += 256) wpre_s[i] = w_pre[i];
    wpsm_s[tid] = w_psm[tid];

    const int ql = tid >> 4;          // 0..15
    const int kb = (tid & 15) * 2;    // 0..30
    const int q = q0 + ql;

    float mreg[16], lreg[16];
#pragma unroll
    for (int g = 0; g < 16; ++g) { mreg[g] = -INFINITY; lreg[g] = 0.f; }

    for (int k0 = kstart; k0 < kend; k0 += 32) {
        float acc0[16], acc1[16];
#pragma unroll
        for (int g = 0; g < 16; ++g) { acc0[g] = 0.f; acc1[g] = 0.f; }

        for (int h = 0; h < H; ++h) {
            {   // stage Q (21 valid rows of 64 f32 -> hi/lo bf16)
                int r = tid >> 3, d = (tid & 7) * 8;
                int qp = q0 - 5 + r;
                float4 a = {0,0,0,0}, b = {0,0,0,0};
                if (r < 21 && qp >= 0) {
                    const float* p = &xq[(h * S + qp) * D + d];
                    a = *(const float4*)p; b = *(const float4*)(p + 4);
                }
                uint4 vh, vl; stage_hilo(a, b, &vh, &vl);
                *(uint4*)&Qs[0][r][d] = vh;
                *(uint4*)&Qs[1][r][d] = vl;
            }
            for (int i = tid; i < 384; i += 256) {  // stage K (42 valid rows)
                int r = i >> 3, d = (i & 7) * 8;
                int kp = k0 - 10 + r;
                float4 a = {0,0,0,0}, b = {0,0,0,0};
                if (r < 42 && kp >= 0) {
                    const float* p = &xk[(h * S + kp) * D + d];
                    a = *(const float4*)p; b = *(const float4*)(p + 4);
                }
                uint4 vh, vl; stage_hilo(a, b, &vh, &vl);
                *(uint4*)&Ks[0][r][d] = vh;
                *(uint4*)&Ks[1][r][d] = vl;
            }
            __syncthreads();  // barA
            {   // MFMA split-bf16: raw = Q·K^T (f32-accurate)
                int w = tid >> 6, l = tid & 63;
                int lr = l & 15, lk = l >> 4;
                for (int t = w; t < 6; t += 4) {
                    int tr = t / 3, tc = t % 3;
                    f32x4 acc = {0.f, 0.f, 0.f, 0.f};
#pragma unroll
                    for (int ks = 0; ks < 2; ++ks) {
                        int db = ks * 32 + lk * 8;
                        bf16x8 ah = *(const bf16x8*)&Qs[0][tr * 16 + lr][db];
                        bf16x8 al = *(const bf16x8*)&Qs[1][tr * 16 + lr][db];
                        bf16x8 bh = *(const bf16x8*)&Ks[0][tc * 16 + lr][db];
                        bf16x8 bl = *(const bf16x8*)&Ks[1][tc * 16 + lr][db];
                        acc = __builtin_amdgcn_mfma_f32_16x16x32_bf16(ah, bh, acc, 0, 0, 0);
                        acc = __builtin_amdgcn_mfma_f32_16x16x32_bf16(ah, bl, acc, 0, 0, 0);
                        acc = __builtin_amdgcn_mfma_f32_16x16x32_bf16(al, bh, acc, 0, 0, 0);
                    }
#pragma unroll
                    for (int i = 0; i < 4; ++i) {
                        int row = tr * 16 + lk * 4 + i;   // C/D: col=lane&15, row=(lane>>4)*4+reg
                        int col = tc * 16 + lr;
                        int qp = q0 - 5 + row, kp = k0 - 10 + col;
                        raws[row][col] = (kp >= 0 && kp <= qp) ? acc[i] * SCALEQK : 0.f;
                    }
                }
            }
            __syncthreads();  // barB
            {   // 6x11 conv (2 adjacent k per thread) + head mix
                float c0 = 0.f, c1 = 0.f;
#pragma unroll
                for (int i2 = 0; i2 < 6; ++i2) {
                    const float* rp = &raws[ql + i2][kb];
                    float v[12];
#pragma unroll
                    for (int j = 0; j < 6; ++j) {
                        float2 t = *(const float2*)(rp + 2 * j);
                        v[2 * j] = t.x; v[2 * j + 1] = t.y;
                    }
                    const float* wp = &wpre_s[h * 66 + i2 * 11];
#pragma unroll
                    for (int j = 0; j < 11; ++j) { c0 += wp[j] * v[j]; c1 += wp[j] * v[j + 1]; }
                }
#pragma unroll
                for (int g = 0; g < 16; ++g) {
                    float wg = wpsm_s[g * 16 + h];
                    acc0[g] += wg * c0; acc1[g] += wg * c1;
                }
            }
            // next barA orders conv reads of raws vs next MFMA writes
        }
        // online m/l update for this thread's 2 columns
        int kk = k0 + kb;
#pragma unroll
        for (int g = 0; g < 16; ++g) {
            if (kk <= q)     online_upd(mreg[g], lreg[g], acc0[g]);
            if (kk + 1 <= q) online_upd(mreg[g], lreg[g], acc1[g]);
        }
    }
    // reduce (m,l) across the 16-lane row group, write partials
#pragma unroll
    for (int g = 0; g < 16; ++g) {
        float m = mreg[g], l = lreg[g];
#pragma unroll
        for (int off = 1; off < 16; off <<= 1) {
            float m2 = __shfl_xor(m, off);
            float l2 = __shfl_xor(l, off);
            float nm = fmaxf(m, m2);
            float t1 = (l  > 0.f) ? l  * __expf(m  - nm) : 0.f;
            float t2 = (l2 > 0.f) ? l2 * __expf(m2 - nm) : 0.f;
            m = nm; l = t1 + t2;
        }
        if ((tid & 15) == 0) {
            mpart[((size_t)kc * H + g) * S + q] = m;
            lpart[((size_t)kc * H + g) * S + q] = l;
        }
    }
}

// Pass 1b: combine chunk partials
__global__ __launch_bounds__(256) void mta_reduce_kernel(
        const float* __restrict__ mpart, const float* __restrict__ lpart,
        float* __restrict__ mrow, float* __restrict__ rlrow) {
    int r = blockIdx.x * 256 + threadIdx.x;
    if (r >= H * S) return;
    int q = r & (S - 1);
    int nkc = (q >> 8) + 1;
    float m = -INFINITY;
    for (int kc = 0; kc < nkc; ++kc) m = fmaxf(m, mpart[(size_t)kc * H * S + r]);
    float l = 0.f;
    for (int kc = 0; kc < nkc; ++kc) {
        float li = lpart[(size_t)kc * H * S + r];
        float mi = mpart[(size_t)kc * H * S + r];
        if (li > 0.f) l += li * __expf(mi - m);
    }
    mrow[r] = m;
    rlrow[r] = 1.f / l;
}

// Pass 2: recompute mixed scores (with halo), normalize, 3x3 conv + w_posm mix, PV.
// block: 8 q rows x 256-k chunk.
__global__ __launch_bounds__(256) void mta_out_kernel(
        const float* __restrict__ xq, const float* __restrict__ xk,
        const float* __restrict__ xv,
        const float* __restrict__ w_pre, const float* __restrict__ w_psm,
        const float* __restrict__ w_post, const float* __restrict__ w_posm,
        const float* __restrict__ mrow, const float* __restrict__ rlrow,
        float* __restrict__ out) {
    const int qt = blockIdx.x, kc = blockIdx.y;
    const int q0 = qt * 8;
    const int kstart = kc * CH;
    if (kstart > q0 + 7) return;
    const int kend = min(kstart + CH, q0 + 8);
    const int tid = threadIdx.x;

    __shared__ unsigned short Qs[2][16][72];  // rows q0-7..q0+8
    __shared__ unsigned short Ks[2][48][72];  // rows k0-12..k0+35
    __shared__ float raws[16][50];
    __shared__ float ps[8][10][35];           // probs, half of g heads at a time
    __shared__ float m2s[16][8][33];
    __shared__ float mst[16][10], rst[16][10];
    __shared__ float wpre_s[16 * 66], wpsm_s[256], wpost_s[144], wposm_s[256];

    for (int i = tid; i < 16 * 66; i += 256) wpre_s[i] = w_pre[i];
    wpsm_s[tid] = w_psm[tid];
    wposm_s[tid] = w_posm[tid];
    if (tid < 144) wpost_s[tid] = w_post[tid];
    for (int i = tid; i < 160; i += 256) {
        int g = i / 10, r = i % 10;
        int qp = q0 - 2 + r;
        if (qp >= 0) { mst[g][r] = mrow[g * S + qp]; rst[g][r] = rlrow[g * S + qp]; }
        else         { mst[g][r] = 0.f; rst[g][r] = 0.f; }
    }

    const int f = tid >> 4, qloc = (tid >> 1) & 7, dh = tid & 1;  // PV mapping
    const int cr = tid / 17, cc = (tid % 17) * 2;                 // conv mapping (tid<170)
    const bool cvalid = tid < 170;
    const int ql2 = tid >> 5, kl = tid & 31;                      // 3x3-conv mapping

    float oacc[32];
#pragma unroll
    for (int i = 0; i < 32; ++i) oacc[i] = 0.f;

    for (int k0 = kstart; k0 < kend; k0 += 32) {
        float a0[16], a1[16];
#pragma unroll
        for (int g = 0; g < 16; ++g) { a0[g] = 0.f; a1[g] = 0.f; }

        for (int h = 0; h < H; ++h) {
            if (tid < 128) {   // stage Q: 16 rows q0-7..q0+8
                int r = tid >> 3, d = (tid & 7) * 8;
                int qp = q0 - 7 + r;
                float4 a = {0,0,0,0}, b = {0,0,0,0};
                if (qp >= 0 && qp < S) {
                    const float* p = &xq[(h * S + qp) * D + d];
                    a = *(const float4*)p; b = *(const float4*)(p + 4);
                }
                uint4 vh, vl; stage_hilo(a, b, &vh, &vl);
                *(uint4*)&Qs[0][r][d] = vh;
                *(uint4*)&Qs[1][r][d] = vl;
            }
            for (int i = tid; i < 384; i += 256) {  // stage K: 48 rows k0-12..k0+35
                int r = i >> 3, d = (i & 7) * 8;
                int kp = k0 - 12 + r;
                float4 a = {0,0,0,0}, b = {0,0,0,0};
                if (kp >= 0 && kp < S) {
                    const float* p = &xk[(h * S + kp) * D + d];
                    a = *(const float4*)p; b = *(const float4*)(p + 4);
                }
                uint4 vh, vl; stage_hilo(a, b, &vh, &vl);
                *(uint4*)&Ks[0][r][d] = vh;
                *(uint4*)&Ks[1][r][d] = vl;
            }
            __syncthreads();  // barA
            {   // MFMA: 1 row-tile x 3 col-tiles
                int w = tid >> 6, l = tid & 63;
                int lr = l & 15, lk = l >> 4;
                if (w < 3) {
                    int tc = w;
                    f32x4 acc = {0.f, 0.f, 0.f, 0.f};
#pragma unroll
                    for (int ks = 0; ks < 2; ++ks) {
                        int db = ks * 32 + lk * 8;
                        bf16x8 ah = *(const bf16x8*)&Qs[0][lr][db];
                        bf16x8 al = *(const bf16x8*)&Qs[1][lr][db];
                        bf16x8 bh = *(const bf16x8*)&Ks[0][tc * 16 + lr][db];
                        bf16x8 bl = *(const bf16x8*)&Ks[1][tc * 16 + lr][db];
                        acc = __builtin_amdgcn_mfma_f32_16x16x32_bf16(ah, bh, acc, 0, 0, 0);
                        acc = __builtin_amdgcn_mfma_f32_16x16x32_bf16(ah, bl, acc, 0, 0, 0);
                        acc = __builtin_amdgcn_mfma_f32_16x16x32_bf16(al, bh, acc, 0, 0, 0);
                    }
#pragma unroll
                    for (int i = 0; i < 4; ++i) {
                        int row = lk * 4 + i, col = tc * 16 + lr;
                        int qp = q0 - 7 + row, kp = k0 - 12 + col;
                        raws[row][col] = (kp >= 0 && kp <= qp) ? acc[i] * SCALEQK : 0.f;
                    }
                }
            }
            __syncthreads();  // barB
            if (cvalid) {     // 6x11 conv on mixed rows q0-2..q0+7, cols k0-2..k0+31
                float c0 = 0.f, c1 = 0.f;
#pragma unroll
                for (int i2 = 0; i2 < 6; ++i2) {
                    const float* rp = &raws[cr + i2][cc];
                    float v[12];
#pragma unroll
                    for (int j = 0; j < 6; ++j) {
                        float2 t = *(const float2*)(rp + 2 * j);
                        v[2 * j] = t.x; v[2 * j + 1] = t.y;
                    }
                    const float* wp = &wpre_s[h * 66 + i2 * 11];
#pragma unroll
                    for (int j = 0; j < 11; ++j) { c0 += wp[j] * v[j]; c1 += wp[j] * v[j + 1]; }
                }
#pragma unroll
                for (int g = 0; g < 16; ++g) {
                    float wg = wpsm_s[g * 16 + h];
                    a0[g] += wg * c0; a1[g] += wg * c1;
                }
            }
        }

        // softmax-normalize + 3x3 conv + w_posm mix, g in two halves of 8
        float m2f[16];
#pragma unroll
        for (int i = 0; i < 16; ++i) m2f[i] = 0.f;

        for (int half = 0; half < 2; ++half) {
            if (cvalid) {
                int qp = q0 - 2 + cr;
                int kp0 = k0 - 2 + cc, kp1 = kp0 + 1;
#pragma unroll
                for (int g8 = 0; g8 < 8; ++g8) {
                    int g = half * 8 + g8;
                    float p0 = 0.f, p1 = 0.f;
                    if (qp >= 0) {
                        float mm = mst[g][cr], rr = rst[g][cr];
                        if (kp0 >= 0 && kp0 <= qp) p0 = __expf(a0[g] - mm) * rr;
                        if (kp1 >= 0 && kp1 <= qp) p1 = __expf(a1[g] - mm) * rr;
                    }
                    ps[g8][cr][cc] = p0;
                    ps[g8][cr][cc + 1] = p1;
                }
            }
            __syncthreads();
            {
                float cg[8];
#pragma unroll
                for (int g8 = 0; g8 < 8; ++g8) {
                    float c = 0.f;
#pragma unroll
                    for (int i2 = 0; i2 < 3; ++i2)
#pragma unroll
                        for (int j2 = 0; j2 < 3; ++j2)
                            c += wpost_s[(half * 8 + g8) * 9 + i2 * 3 + j2] * ps[g8][ql2 + i2][kl + j2];
                    cg[g8] = c;
                }
#pragma unroll
                for (int ff = 0; ff < 16; ++ff) {
                    float s = 0.f;
#pragma unroll
                    for (int g8 = 0; g8 < 8; ++g8) s += wposm_s[ff * 16 + half * 8 + g8] * cg[g8];
                    m2f[ff] += s;
                }
            }
            if (half == 0) __syncthreads();  // protect ps before next half overwrites
        }
        {   // write mixed probs
            int q = q0 + ql2, k = k0 + kl;
            bool valid = (k <= q) && (k < kend);
#pragma unroll
            for (int ff = 0; ff < 16; ++ff) m2s[ff][ql2][kl] = valid ? m2f[ff] : 0.f;
        }
        __syncthreads();
        // PV
        for (int kl2 = 0; kl2 < 32; ++kl2) {
            int k = k0 + kl2;
            if (k >= kend) break;
            float s = m2s[f][qloc][kl2];
            if (s != 0.f) {
                const float* vp = &xv[(f * S + k) * D + dh * 32];
#pragma unroll
                for (int d4 = 0; d4 < 8; ++d4) {
                    float4 v = *(const float4*)(vp + d4 * 4);
                    oacc[d4 * 4 + 0] += s * v.x;
                    oacc[d4 * 4 + 1] += s * v.y;
                    oacc[d4 * 4 + 2] += s * v.z;
                    oacc[d4 * 4 + 3] += s * v.w;
                }
            }
        }
        __syncthreads();
    }

    int q = q0 + qloc;
    float* op = out + ((size_t)q * H + f) * D + dh * 32;
#pragma unroll
    for (int i = 0; i < 32; ++i) atomicAdd(op + i, oacc[i]);
}

extern "C" void kernel_launch(void* const* d_in, const int* in_sizes, int n_in,
                              void* d_out, int out_size, void* d_ws, size_t ws_size,
                              hipStream_t stream) {
    const float* xq     = (const float*)d_in[0];
    const float* xk     = (const float*)d_in[1];
    const float* xv     = (const float*)d_in[2];
    const float* w_pre  = (const float*)d_in[4];
    const float* w_post = (const float*)d_in[5];
    const float* w_psm  = (const float*)d_in[6];
    const float* w_posm = (const float*)d_in[7];
    float* out = (float*)d_out;

    // ws: mpart[8][16][2048] | lpart[8][16][2048] | mrow[16*2048] | rlrow[16*2048] = 2.25 MiB
    float* mpart = (float*)d_ws;
    float* lpart = mpart + (size_t)8 * H * S;
    float* mrow  = lpart + (size_t)8 * H * S;
    float* rlrow = mrow + (size_t)H * S;

    hipMemsetAsync(d_out, 0, sizeof(float) * (size_t)out_size, stream);

    dim3 g1(8, 128);   // kc, qt(16 rows)
    mta_stats_kernel<<<g1, 256, 0, stream>>>(xq, xk, w_pre, w_psm, mpart, lpart);

    mta_reduce_kernel<<<128, 256, 0, stream>>>(mpart, lpart, mrow, rlrow);

    dim3 g2(256, 8);   // qt(8 rows), kc
    mta_out_kernel<<<g2, 256, 0, stream>>>(xq, xk, xv, w_pre, w_psm, w_post, w_posm,
                                           mrow, rlrow, out);
}

// Round 3
// 1575.186 us; speedup vs baseline: 2.1141x; 2.1141x over previous
//
#include <hip/hip_runtime.h>
#include <math.h>

#define H 16
#define S 2048
#define D 64
#define SCALEQK 0.125f
#define CH 256

typedef __attribute__((ext_vector_type(4))) float f32x4;
typedef __attribute__((ext_vector_type(8))) short bf16x8;

__device__ inline float h2f(unsigned short b) {
    _Float16 h; __builtin_memcpy(&h, &b, 2); return (float)h;
}
__device__ inline unsigned short f2h(float x) {
    _Float16 h = (_Float16)x; unsigned short b; __builtin_memcpy(&b, &h, 2); return b;
}

// split f32 -> bf16 hi + bf16 lo (residual), rne; packed into two uint4 (8 elems)
__device__ inline void stage_hilo(float4 a, float4 b, uint4* vh, uint4* vl) {
    float xs[8] = {a.x, a.y, a.z, a.w, b.x, b.y, b.z, b.w};
    unsigned int hh[8], ll[8];
#pragma unroll
    for (int j = 0; j < 8; ++j) {
        unsigned int u = __float_as_uint(xs[j]);
        unsigned int h = (u + 0x7fffu + ((u >> 16) & 1u)) >> 16;
        float r = xs[j] - __uint_as_float(h << 16);
        unsigned int u2 = __float_as_uint(r);
        hh[j] = h;
        ll[j] = (u2 + 0x7fffu + ((u2 >> 16) & 1u)) >> 16;
    }
    uint4 h4, l4;
    h4.x = hh[0] | (hh[1] << 16); h4.y = hh[2] | (hh[3] << 16);
    h4.z = hh[4] | (hh[5] << 16); h4.w = hh[6] | (hh[7] << 16);
    l4.x = ll[0] | (ll[1] << 16); l4.y = ll[2] | (ll[3] << 16);
    l4.z = ll[4] | (ll[5] << 16); l4.w = ll[6] | (ll[7] << 16);
    *vh = h4; *vl = l4;
}

__device__ inline void online_upd(float& m, float& l, float x) {
    if (x > m) { l = l * __expf(m - x) + 1.f; m = x; }
    else       { l += __expf(x - m); }
}

// ---------------------------------------------------------------------------
// K_cvt: f32 src -> (hi, lo) bf16 split arrays, optional scale. 8 elems/thread.
__global__ __launch_bounds__(256) void mta_cvt_kernel(const float* __restrict__ src,
                                                      unsigned short* __restrict__ hi,
                                                      unsigned short* __restrict__ lo,
                                                      float scale, int n8) {
    int i = blockIdx.x * 256 + threadIdx.x;
    int stride = gridDim.x * 256;
    for (; i < n8; i += stride) {
        const float* p = src + (size_t)i * 8;
        float4 a = *(const float4*)p;
        float4 b = *(const float4*)(p + 4);
        a.x *= scale; a.y *= scale; a.z *= scale; a.w *= scale;
        b.x *= scale; b.y *= scale; b.z *= scale; b.w *= scale;
        uint4 vh, vl; stage_hilo(a, b, &vh, &vl);
        *(uint4*)&hi[(size_t)i * 8] = vh;
        *(uint4*)&lo[(size_t)i * 8] = vl;
    }
}

// ---------------------------------------------------------------------------
// Pass 1: mixed scores (QK^T split-bf16 MFMA + 6x11 causal conv + w_psm mix)
// written as f16 to the stripe score buffer. 16 q rows x 256-k chunk per block.
// Software-pipelined over heads: 1 barrier per head.
__global__ __launch_bounds__(256) void mta_score_kernel(
        const unsigned short* __restrict__ qhi, const unsigned short* __restrict__ qlo,
        const unsigned short* __restrict__ khi, const unsigned short* __restrict__ klo,
        const float* __restrict__ w_pre, const float* __restrict__ w_psm,
        unsigned short* __restrict__ sc, int qs, int SQ) {
    const int kc = blockIdx.x, qt = blockIdx.y;
    const int q0 = qs - 16 + qt * 16;          // tile 0 is the halo tile
    const int kstart = kc * CH;
    if (kstart > q0 + 15) return;
    const int kend = min(kstart + CH, q0 + 16);
    const int tid = threadIdx.x;

    __shared__ unsigned short Qs[2][2][32][72];  // [buf][hi/lo][row][col]
    __shared__ unsigned short Ks[2][2][48][72];
    __shared__ float raws[2][32][48];
    __shared__ float wpre_s[16 * 66];
    __shared__ float wpsm_s[256];

    for (int i = tid; i < 16 * 66; i += 256) wpre_s[i] = w_pre[i];
    wpsm_s[tid] = w_psm[tid];

    const int ql = tid >> 4;          // 0..15
    const int kb = (tid & 15) * 2;    // 0..30
    const int q = q0 + ql;
    const int rowl = q - (qs - 16);   // local buffer row

#define STAGE1(hh, bb) do { \
        int r_ = tid >> 3, d_ = (tid & 7) * 8; \
        int qp_ = q0 - 5 + r_; \
        uint4 vh_ = {0,0,0,0}, vl_ = {0,0,0,0}; \
        if (r_ < 21 && qp_ >= 0) { \
            size_t off_ = ((size_t)(hh) * S + qp_) * D + d_; \
            vh_ = *(const uint4*)&qhi[off_]; vl_ = *(const uint4*)&qlo[off_]; } \
        *(uint4*)&Qs[bb][0][r_][d_] = vh_; *(uint4*)&Qs[bb][1][r_][d_] = vl_; \
        for (int i_ = tid; i_ < 384; i_ += 256) { \
            int rr_ = i_ >> 3, dd_ = (i_ & 7) * 8; \
            int kp_ = k0 - 10 + rr_; \
            uint4 wh_ = {0,0,0,0}, wl_ = {0,0,0,0}; \
            if (rr_ < 42 && kp_ >= 0 && kp_ < S) { \
                size_t off_ = ((size_t)(hh) * S + kp_) * D + dd_; \
                wh_ = *(const uint4*)&khi[off_]; wl_ = *(const uint4*)&klo[off_]; } \
            *(uint4*)&Ks[bb][0][rr_][dd_] = wh_; *(uint4*)&Ks[bb][1][rr_][dd_] = wl_; } \
    } while (0)

#define MFMA1(bb) do { \
        int w_ = tid >> 6, l_ = tid & 63; \
        int lr_ = l_ & 15, lk_ = l_ >> 4; \
        for (int t_ = w_; t_ < 6; t_ += 4) { \
            int tr_ = t_ / 3, tc_ = t_ % 3; \
            f32x4 acc_ = {0.f, 0.f, 0.f, 0.f}; \
            _Pragma("unroll") \
            for (int ks_ = 0; ks_ < 2; ++ks_) { \
                int db_ = ks_ * 32 + lk_ * 8; \
                bf16x8 ah_ = *(const bf16x8*)&Qs[bb][0][tr_ * 16 + lr_][db_]; \
                bf16x8 al_ = *(const bf16x8*)&Qs[bb][1][tr_ * 16 + lr_][db_]; \
                bf16x8 bh_ = *(const bf16x8*)&Ks[bb][0][tc_ * 16 + lr_][db_]; \
                bf16x8 bl_ = *(const bf16x8*)&Ks[bb][1][tc_ * 16 + lr_][db_]; \
                acc_ = __builtin_amdgcn_mfma_f32_16x16x32_bf16(ah_, bh_, acc_, 0, 0, 0); \
                acc_ = __builtin_amdgcn_mfma_f32_16x16x32_bf16(ah_, bl_, acc_, 0, 0, 0); \
                acc_ = __builtin_amdgcn_mfma_f32_16x16x32_bf16(al_, bh_, acc_, 0, 0, 0); \
            } \
            _Pragma("unroll") \
            for (int i_ = 0; i_ < 4; ++i_) { \
                int row_ = tr_ * 16 + lk_ * 4 + i_, col_ = tc_ * 16 + lr_; \
                int qp_ = q0 - 5 + row_, kp_ = k0 - 10 + col_; \
                raws[bb][row_][col_] = (kp_ >= 0 && kp_ <= qp_) ? acc_[i_] : 0.f; \
            } \
        } \
    } while (0)

#define CONV1(hc, bb) do { \
        float c0_ = 0.f, c1_ = 0.f; \
        _Pragma("unroll") \
        for (int i2_ = 0; i2_ < 6; ++i2_) { \
            const float* rp_ = &raws[bb][ql + i2_][kb]; \
            float v_[12]; \
            _Pragma("unroll") \
            for (int j_ = 0; j_ < 6; ++j_) { \
                float2 t_ = *(const float2*)(rp_ + 2 * j_); \
                v_[2 * j_] = t_.x; v_[2 * j_ + 1] = t_.y; } \
            const float* wp_ = &wpre_s[(hc) * 66 + i2_ * 11]; \
            _Pragma("unroll") \
            for (int j_ = 0; j_ < 11; ++j_) { c0_ += wp_[j_] * v_[j_]; c1_ += wp_[j_] * v_[j_ + 1]; } \
        } \
        _Pragma("unroll") \
        for (int g_ = 0; g_ < 16; ++g_) { \
            float wg_ = wpsm_s[g_ * 16 + (hc)]; \
            acc0[g_] += wg_ * c0_; acc1[g_] += wg_ * c1_; \
        } \
    } while (0)

    for (int k0 = kstart; k0 < kend; k0 += 32) {
        float acc0[16], acc1[16];
#pragma unroll
        for (int g = 0; g < 16; ++g) { acc0[g] = 0.f; acc1[g] = 0.f; }

        STAGE1(0, 0);
        __syncthreads();
        for (int h = 0; h < 16; ++h) {
            MFMA1(h & 1);
            if (h < 15) STAGE1(h + 1, (h + 1) & 1);
            if (h > 0) CONV1(h - 1, (h - 1) & 1);
            __syncthreads();
        }
        CONV1(15, 1);

        // write f16 scores (0 above diagonal; never read there)
        int kk = k0 + kb;
        unsigned int pack = (unsigned int)f2h((kk <= q) ? acc0[0] : 0.f);  // placeholder init
#pragma unroll
        for (int g = 0; g < 16; ++g) {
            unsigned short h0 = f2h((kk <= q) ? acc0[g] : 0.f);
            unsigned short h1 = f2h((kk + 1 <= q) ? acc1[g] : 0.f);
            pack = (unsigned int)h0 | ((unsigned int)h1 << 16);
            *(unsigned int*)&sc[((size_t)(g * (SQ + 16) + rowl)) * S + kk] = pack;
        }
        __syncthreads();  // raws/Qs reuse next k-step
    }
#undef STAGE1
#undef MFMA1
#undef CONV1
}

// ---------------------------------------------------------------------------
// Stats: per (g,q) row of the stripe, m = max, l = sum exp(x-m) over k<=q.
// One wave per row, reads f16 scores.
__global__ __launch_bounds__(256) void mta_rowstats_kernel(
        const unsigned short* __restrict__ sc,
        float* __restrict__ mrow, float* __restrict__ rlrow, int qs, int SQ) {
    int row = blockIdx.x * 4 + (threadIdx.x >> 6);
    int lane = threadIdx.x & 63;
    int g = row / SQ, qq = row % SQ;
    int q = qs + qq;
    const unsigned short* rp = sc + ((size_t)(g * (SQ + 16) + qq + 16)) * S;

    float v[32];
#pragma unroll
    for (int it = 0; it < 4; ++it) {
        int kbase = it * 512 + lane * 8;
        if (it * 512 <= q) {
            uint4 u = *(const uint4*)&rp[kbase];
            unsigned int ws[4] = {u.x, u.y, u.z, u.w};
#pragma unroll
            for (int j = 0; j < 4; ++j) {
                float x0 = h2f((unsigned short)(ws[j] & 0xffff));
                float x1 = h2f((unsigned short)(ws[j] >> 16));
                v[it * 8 + 2 * j]     = (kbase + 2 * j     <= q) ? x0 : -INFINITY;
                v[it * 8 + 2 * j + 1] = (kbase + 2 * j + 1 <= q) ? x1 : -INFINITY;
            }
        } else {
#pragma unroll
            for (int j = 0; j < 8; ++j) v[it * 8 + j] = -INFINITY;
        }
    }
    float m = -INFINITY;
#pragma unroll
    for (int j = 0; j < 32; ++j) m = fmaxf(m, v[j]);
#pragma unroll
    for (int off = 1; off < 64; off <<= 1) m = fmaxf(m, __shfl_xor(m, off));
    float l = 0.f;
#pragma unroll
    for (int j = 0; j < 32; ++j) l += __expf(v[j] - m);   // exp(-inf - m) = 0
#pragma unroll
    for (int off = 1; off < 64; off <<= 1) l += __shfl_xor(l, off);
    if (lane == 0) { mrow[g * S + q] = m; rlrow[g * S + q] = 1.f / l; }
}

// ---------------------------------------------------------------------------
// Pass 2: probs = exp(sc - m)/l, 3x3 causal conv, w_posm mix, PV.
// 8 q rows x 256-k chunk per block. No QK recompute.
__global__ __launch_bounds__(256) void mta_out2_kernel(
        const unsigned short* __restrict__ sc,
        const float* __restrict__ mrow, const float* __restrict__ rlrow,
        const float* __restrict__ xv,
        const float* __restrict__ w_post, const float* __restrict__ w_posm,
        float* __restrict__ out, int qs, int SQ) {
    const int qt = blockIdx.x, kc = blockIdx.y;
    const int q0 = qs + qt * 8;
    const int kstart = kc * CH;
    if (kstart > q0 + 7) return;
    const int kend = min(kstart + CH, q0 + 8);
    const int tid = threadIdx.x;

    __shared__ float ps[16][10][36];
    __shared__ float m2s[16][8][33];
    __shared__ float mst[16][10], rst[16][10];
    __shared__ float wpost_s[144], wposm_s[256];

    wposm_s[tid] = w_posm[tid];
    if (tid < 144) wpost_s[tid] = w_post[tid];
    for (int i = tid; i < 160; i += 256) {
        int g = i / 10, r = i % 10;
        int qp = q0 - 2 + r;
        if (qp >= 0) { mst[g][r] = mrow[g * S + qp]; rst[g][r] = rlrow[g * S + qp]; }
        else         { mst[g][r] = 0.f; rst[g][r] = 0.f; }
    }
    __syncthreads();

    const int f = tid >> 4, qloc = (tid >> 1) & 7, dh = tid & 1;  // PV mapping
    const int ql2 = tid >> 5, kl = tid & 31;                      // conv mapping

    float oacc[32];
#pragma unroll
    for (int i = 0; i < 32; ++i) oacc[i] = 0.f;

    for (int k0 = kstart; k0 < kend; k0 += 32) {
        // stage normalized probs with halo: 16g x 10r x 34c (as 17 pairs)
        for (int i = tid; i < 2720; i += 256) {
            int g = i / 170, rem = i % 170;
            int r = rem / 17, c2 = (rem % 17) * 2;
            int qp = q0 - 2 + r;
            int kp = k0 - 2 + c2;
            float p0 = 0.f, p1 = 0.f;
            if (qp >= 0 && kp >= 0) {
                unsigned int u = *(const unsigned int*)
                    &sc[((size_t)(g * (SQ + 16) + qp - (qs - 16))) * S + kp];
                float mm = mst[g][r], rr = rst[g][r];
                if (kp <= qp)     p0 = __expf(h2f((unsigned short)(u & 0xffff)) - mm) * rr;
                if (kp + 1 <= qp) p1 = __expf(h2f((unsigned short)(u >> 16)) - mm) * rr;
            }
            ps[g][r][c2] = p0;
            ps[g][r][c2 + 1] = p1;
        }
        __syncthreads();
        // 3x3 conv + w_posm mix
        {
            int q = q0 + ql2, k = k0 + kl;
            bool valid = (k <= q) && (k < kend);
            float cg[16];
#pragma unroll
            for (int g = 0; g < 16; ++g) {
                float c = 0.f;
#pragma unroll
                for (int i2 = 0; i2 < 3; ++i2)
#pragma unroll
                    for (int j2 = 0; j2 < 3; ++j2)
                        c += wpost_s[g * 9 + i2 * 3 + j2] * ps[g][ql2 + i2][kl + j2];
                cg[g] = c;
            }
#pragma unroll
            for (int ff = 0; ff < 16; ++ff) {
                float s = 0.f;
#pragma unroll
                for (int g = 0; g < 16; ++g) s += wposm_s[ff * 16 + g] * cg[g];
                m2s[ff][ql2][kl] = valid ? s : 0.f;
            }
        }
        __syncthreads();
        // PV
        for (int kl2 = 0; kl2 < 32; ++kl2) {
            int k = k0 + kl2;
            if (k >= kend) break;
            float s = m2s[f][qloc][kl2];
            if (s != 0.f) {
                const float* vp = &xv[((size_t)f * S + k) * D + dh * 32];
#pragma unroll
                for (int d4 = 0; d4 < 8; ++d4) {
                    float4 v = *(const float4*)(vp + d4 * 4);
                    oacc[d4 * 4 + 0] += s * v.x;
                    oacc[d4 * 4 + 1] += s * v.y;
                    oacc[d4 * 4 + 2] += s * v.z;
                    oacc[d4 * 4 + 3] += s * v.w;
                }
            }
        }
        __syncthreads();
    }

    int q = q0 + qloc;
    float* op = out + ((size_t)q * H + f) * D + dh * 32;
#pragma unroll
    for (int i = 0; i < 32; ++i) atomicAdd(op + i, oacc[i]);
}

// ===========================================================================
// Fallback path (round-2 kernels, verbatim): used when ws_size is too small.
// ===========================================================================
__global__ __launch_bounds__(256) void fb_stats_kernel(
        const float* __restrict__ xq, const float* __restrict__ xk,
        const float* __restrict__ w_pre, const float* __restrict__ w_psm,
        float* __restrict__ mpart, float* __restrict__ lpart) {
    const int kc = blockIdx.x, qt = blockIdx.y;
    const int q0 = qt * 16;
    const int kstart = kc * CH;
    if (kstart > q0 + 15) return;
    const int kend = min(kstart + CH, q0 + 16);
    const int tid = threadIdx.x;

    __shared__ unsigned short Qs[2][32][72];
    __shared__ unsigned short Ks[2][48][72];
    __shared__ float raws[32][50];
    __shared__ float wpre_s[16 * 66];
    __shared__ float wpsm_s[256];

    for (int i = tid; i < 16 * 66; i += 256) wpre_s[i] = w_pre[i];
    wpsm_s[tid] = w_psm[tid];

    const int ql = tid >> 4;
    const int kb = (tid & 15) * 2;
    const int q = q0 + ql;

    float mreg[16], lreg[16];
#pragma unroll
    for (int g = 0; g < 16; ++g) { mreg[g] = -INFINITY; lreg[g] = 0.f; }

    for (int k0 = kstart; k0 < kend; k0 += 32) {
        float acc0[16], acc1[16];
#pragma unroll
        for (int g = 0; g < 16; ++g) { acc0[g] = 0.f; acc1[g] = 0.f; }

        for (int h = 0; h < H; ++h) {
            {
                int r = tid >> 3, d = (tid & 7) * 8;
                int qp = q0 - 5 + r;
                float4 a = {0,0,0,0}, b = {0,0,0,0};
                if (r < 21 && qp >= 0) {
                    const float* p = &xq[(h * S + qp) * D + d];
                    a = *(const float4*)p; b = *(const float4*)(p + 4);
                }
                uint4 vh, vl; stage_hilo(a, b, &vh, &vl);
                *(uint4*)&Qs[0][r][d] = vh;
                *(uint4*)&Qs[1][r][d] = vl;
            }
            for (int i = tid; i < 384; i += 256) {
                int r = i >> 3, d = (i & 7) * 8;
                int kp = k0 - 10 + r;
                float4 a = {0,0,0,0}, b = {0,0,0,0};
                if (r < 42 && kp >= 0) {
                    const float* p = &xk[(h * S + kp) * D + d];
                    a = *(const float4*)p; b = *(const float4*)(p + 4);
                }
                uint4 vh, vl; stage_hilo(a, b, &vh, &vl);
                *(uint4*)&Ks[0][r][d] = vh;
                *(uint4*)&Ks[1][r][d] = vl;
            }
            __syncthreads();
            {
                int w = tid >> 6, l = tid & 63;
                int lr = l & 15, lk = l >> 4;
                for (int t = w; t < 6; t += 4) {
                    int tr = t / 3, tc = t % 3;
                    f32x4 acc = {0.f, 0.f, 0.f, 0.f};
#pragma unroll
                    for (int ks = 0; ks < 2; ++ks) {
                        int db = ks * 32 + lk * 8;
                        bf16x8 ah = *(const bf16x8*)&Qs[0][tr * 16 + lr][db];
                        bf16x8 al = *(const bf16x8*)&Qs[1][tr * 16 + lr][db];
                        bf16x8 bh = *(const bf16x8*)&Ks[0][tc * 16 + lr][db];
                        bf16x8 bl = *(const bf16x8*)&Ks[1][tc * 16 + lr][db];
                        acc = __builtin_amdgcn_mfma_f32_16x16x32_bf16(ah, bh, acc, 0, 0, 0);
                        acc = __builtin_amdgcn_mfma_f32_16x16x32_bf16(ah, bl, acc, 0, 0, 0);
                        acc = __builtin_amdgcn_mfma_f32_16x16x32_bf16(al, bh, acc, 0, 0, 0);
                    }
#pragma unroll
                    for (int i = 0; i < 4; ++i) {
                        int row = tr * 16 + lk * 4 + i;
                        int col = tc * 16 + lr;
                        int qp = q0 - 5 + row, kp = k0 - 10 + col;
                        raws[row][col] = (kp >= 0 && kp <= qp) ? acc[i] * SCALEQK : 0.f;
                    }
                }
            }
            __syncthreads();
            {
                float c0 = 0.f, c1 = 0.f;
#pragma unroll
                for (int i2 = 0; i2 < 6; ++i2) {
                    const float* rp = &raws[ql + i2][kb];
                    float v[12];
#pragma unroll
                    for (int j = 0; j < 6; ++j) {
                        float2 t = *(const float2*)(rp + 2 * j);
                        v[2 * j] = t.x; v[2 * j + 1] = t.y;
                    }
                    const float* wp = &wpre_s[h * 66 + i2 * 11];
#pragma unroll
                    for (int j = 0; j < 11; ++j) { c0 += wp[j] * v[j]; c1 += wp[j] * v[j + 1]; }
                }
#pragma unroll
                for (int g = 0; g < 16; ++g) {
                    float wg = wpsm_s[g * 16 + h];
                    acc0[g] += wg * c0; acc1[g] += wg * c1;
                }
            }
        }
        int kk = k0 + kb;
#pragma unroll
        for (int g = 0; g < 16; ++g) {
            if (kk <= q)     online_upd(mreg[g], lreg[g], acc0[g]);
            if (kk + 1 <= q) online_upd(mreg[g], lreg[g], acc1[g]);
        }
    }
#pragma unroll
    for (int g = 0; g < 16; ++g) {
        float m = mreg[g], l = lreg[g];
#pragma unroll
        for (int off = 1; off < 16; off <<= 1) {
            float m2 = __shfl_xor(m, off);
            float l2 = __shfl_xor(l, off);
            float nm = fmaxf(m, m2);
            float t1 = (l  > 0.f) ? l  * __expf(m  - nm) : 0.f;
            float t2 = (l2 > 0.f) ? l2 * __expf(m2 - nm) : 0.f;
            m = nm; l = t1 + t2;
        }
        if ((tid & 15) == 0) {
            mpart[((size_t)kc * H + g) * S + q] = m;
            lpart[((size_t)kc * H + g) * S + q] = l;
        }
    }
}

__global__ __launch_bounds__(256) void fb_reduce_kernel(
        const float* __restrict__ mpart, const float* __restrict__ lpart,
        float* __restrict__ mrow, float* __restrict__ rlrow) {
    int r = blockIdx.x * 256 + threadIdx.x;
    if (r >= H * S) return;
    int q = r & (S - 1);
    int nkc = (q >> 8) + 1;
    float m = -INFINITY;
    for (int kc = 0; kc < nkc; ++kc) m = fmaxf(m, mpart[(size_t)kc * H * S + r]);
    float l = 0.f;
    for (int kc = 0; kc < nkc; ++kc) {
        float li = lpart[(size_t)kc * H * S + r];
        float mi = mpart[(size_t)kc * H * S + r];
        if (li > 0.f) l += li * __expf(mi - m);
    }
    mrow[r] = m;
    rlrow[r] = 1.f / l;
}

__global__ __launch_bounds__(256) void fb_out_kernel(
        const float* __restrict__ xq, const float* __restrict__ xk,
        const float* __restrict__ xv,
        const float* __restrict__ w_pre, const float* __restrict__ w_psm,
        const float* __restrict__ w_post, const float* __restrict__ w_posm,
        const float* __restrict__ mrow, const float* __restrict__ rlrow,
        float* __restrict__ out) {
    const int qt = blockIdx.x, kc = blockIdx.y;
    const int q0 = qt * 8;
    const int kstart = kc * CH;
    if (kstart > q0 + 7) return;
    const int kend = min(kstart + CH, q0 + 8);
    const int tid = threadIdx.x;

    __shared__ unsigned short Qs[2][16][72];
    __shared__ unsigned short Ks[2][48][72];
    __shared__ float raws[16][50];
    __shared__ float ps[8][10][35];
    __shared__ float m2s[16][8][33];
    __shared__ float mst[16][10], rst[16][10];
    __shared__ float wpre_s[16 * 66], wpsm_s[256], wpost_s[144], wposm_s[256];

    for (int i = tid; i < 16 * 66; i += 256) wpre_s[i] = w_pre[i];
    wpsm_s[tid] = w_psm[tid];
    wposm_s[tid] = w_posm[tid];
    if (tid < 144) wpost_s[tid] = w_post[tid];
    for (int i = tid; i < 160; i += 256) {
        int g = i / 10, r = i % 10;
        int qp = q0 - 2 + r;
        if (qp >= 0) { mst[g][r] = mrow[g * S + qp]; rst[g][r] = rlrow[g * S + qp]; }
        else         { mst[g][r] = 0.f; rst[g][r] = 0.f; }
    }

    const int f = tid >> 4, qloc = (tid >> 1) & 7, dh = tid & 1;
    const int cr = tid / 17, cc = (tid % 17) * 2;
    const bool cvalid = tid < 170;
    const int ql2 = tid >> 5, kl = tid & 31;

    float oacc[32];
#pragma unroll
    for (int i = 0; i < 32; ++i) oacc[i] = 0.f;

    for (int k0 = kstart; k0 < kend; k0 += 32) {
        float a0[16], a1[16];
#pragma unroll
        for (int g = 0; g < 16; ++g) { a0[g] = 0.f; a1[g] = 0.f; }

        for (int h = 0; h < H; ++h) {
            if (tid < 128) {
                int r = tid >> 3, d = (tid & 7) * 8;
                int qp = q0 - 7 + r;
                float4 a = {0,0,0,0}, b = {0,0,0,0};
                if (qp >= 0 && qp < S) {
                    const float* p = &xq[(h * S + qp) * D + d];
                    a = *(const float4*)p; b = *(const float4*)(p + 4);
                }
                uint4 vh, vl; stage_hilo(a, b, &vh, &vl);
                *(uint4*)&Qs[0][r][d] = vh;
                *(uint4*)&Qs[1][r][d] = vl;
            }
            for (int i = tid; i < 384; i += 256) {
                int r = i >> 3, d = (i & 7) * 8;
                int kp = k0 - 12 + r;
                float4 a = {0,0,0,0}, b = {0,0,0,0};
                if (kp >= 0 && kp < S) {
                    const float* p = &xk[(h * S + kp) * D + d];
                    a = *(const float4*)p; b = *(const float4*)(p + 4);
                }
                uint4 vh, vl; stage_hilo(a, b, &vh, &vl);
                *(uint4*)&Ks[0][r][d] = vh;
                *(uint4*)&Ks[1][r][d] = vl;
            }
            __syncthreads();
            {
                int w = tid >> 6, l = tid & 63;
                int lr = l & 15, lk = l >> 4;
                if (w < 3) {
                    int tc = w;
                    f32x4 acc = {0.f, 0.f, 0.f, 0.f};
#pragma unroll
                    for (int ks = 0; ks < 2; ++ks) {
                        int db = ks * 32 + lk * 8;
                        bf16x8 ah = *(const bf16x8*)&Qs[0][lr][db];
                        bf16x8 al = *(const bf16x8*)&Qs[1][lr][db];
                        bf16x8 bh = *(const bf16x8*)&Ks[0][tc * 16 + lr][db];
                        bf16x8 bl = *(const bf16x8*)&Ks[1][tc * 16 + lr][db];
                        acc = __builtin_amdgcn_mfma_f32_16x16x32_bf16(ah, bh, acc, 0, 0, 0);
                        acc = __builtin_amdgcn_mfma_f32_16x16x32_bf16(ah, bl, acc, 0, 0, 0);
                        acc = __builtin_amdgcn_mfma_f32_16x16x32_bf16(al, bh, acc, 0, 0, 0);
                    }
#pragma unroll
                    for (int i = 0; i < 4; ++i) {
                        int row = lk * 4 + i, col = tc * 16 + lr;
                        int qp = q0 - 7 + row, kp = k0 - 12 + col;
                        raws[row][col] = (kp >= 0 && kp <= qp) ? acc[i] * SCALEQK : 0.f;
                    }
                }
            }
            __syncthreads();
            if (cvalid) {
                float c0 = 0.f, c1 = 0.f;
#pragma unroll
                for (int i2 = 0; i2 < 6; ++i2) {
                    const float* rp = &raws[cr + i2][cc];
                    float v[12];
#pragma unroll
                    for (int j = 0; j < 6; ++j) {
                        float2 t = *(const float2*)(rp + 2 * j);
                        v[2 * j] = t.x; v[2 * j + 1] = t.y;
                    }
                    const float* wp = &wpre_s[h * 66 + i2 * 11];
#pragma unroll
                    for (int j = 0; j < 11; ++j) { c0 += wp[j] * v[j]; c1 += wp[j] * v[j + 1]; }
                }
#pragma unroll
                for (int g = 0; g < 16; ++g) {
                    float wg = wpsm_s[g * 16 + h];
                    a0[g] += wg * c0; a1[g] += wg * c1;
                }
            }
        }

        float m2f[16];
#pragma unroll
        for (int i = 0; i < 16; ++i) m2f[i] = 0.f;

        for (int half = 0; half < 2; ++half) {
            if (cvalid) {
                int qp = q0 - 2 + cr;
                int kp0 = k0 - 2 + cc, kp1 = kp0 + 1;
#pragma unroll
                for (int g8 = 0; g8 < 8; ++g8) {
                    int g = half * 8 + g8;
                    float p0 = 0.f, p1 = 0.f;
                    if (qp >= 0) {
                        float mm = mst[g][cr], rr = rst[g][cr];
                        if (kp0 >= 0 && kp0 <= qp) p0 = __expf(a0[g] - mm) * rr;
                        if (kp1 >= 0 && kp1 <= qp) p1 = __expf(a1[g] - mm) * rr;
                    }
                    ps[g8][cr][cc] = p0;
                    ps[g8][cr][cc + 1] = p1;
                }
            }
            __syncthreads();
            {
                float cg[8];
#pragma unroll
                for (int g8 = 0; g8 < 8; ++g8) {
                    float c = 0.f;
#pragma unroll
                    for (int i2 = 0; i2 < 3; ++i2)
#pragma unroll
                        for (int j2 = 0; j2 < 3; ++j2)
                            c += wpost_s[(half * 8 + g8) * 9 + i2 * 3 + j2] * ps[g8][ql2 + i2][kl + j2];
                    cg[g8] = c;
                }
#pragma unroll
                for (int ff = 0; ff < 16; ++ff) {
                    float s = 0.f;
#pragma unroll
                    for (int g8 = 0; g8 < 8; ++g8) s += wposm_s[ff * 16 + half * 8 + g8] * cg[g8];
                    m2f[ff] += s;
                }
            }
            if (half == 0) __syncthreads();
        }
        {
            int q = q0 + ql2, k = k0 + kl;
            bool valid = (k <= q) && (k < kend);
#pragma unroll
            for (int ff = 0; ff < 16; ++ff) m2s[ff][ql2][kl] = valid ? m2f[ff] : 0.f;
        }
        __syncthreads();
        for (int kl2 = 0; kl2 < 32; ++kl2) {
            int k = k0 + kl2;
            if (k >= kend) break;
            float s = m2s[f][qloc][kl2];
            if (s != 0.f) {
                const float* vp = &xv[(f * S + k) * D + dh * 32];
#pragma unroll
                for (int d4 = 0; d4 < 8; ++d4) {
                    float4 v = *(const float4*)(vp + d4 * 4);
                    oacc[d4 * 4 + 0] += s * v.x;
                    oacc[d4 * 4 + 1] += s * v.y;
                    oacc[d4 * 4 + 2] += s * v.z;
                    oacc[d4 * 4 + 3] += s * v.w;
                }
            }
        }
        __syncthreads();
    }

    int q = q0 + qloc;
    float* op = out + ((size_t)q * H + f) * D + dh * 32;
#pragma unroll
    for (int i = 0; i < 32; ++i) atomicAdd(op + i, oacc[i]);
}

// ===========================================================================
extern "C" void kernel_launch(void* const* d_in, const int* in_sizes, int n_in,
                              void* d_out, int out_size, void* d_ws, size_t ws_size,
                              hipStream_t stream) {
    const float* xq     = (const float*)d_in[0];
    const float* xk     = (const float*)d_in[1];
    const float* xv     = (const float*)d_in[2];
    const float* w_pre  = (const float*)d_in[4];
    const float* w_post = (const float*)d_in[5];
    const float* w_psm  = (const float*)d_in[6];
    const float* w_posm = (const float*)d_in[7];
    float* out = (float*)d_out;

    hipMemsetAsync(d_out, 0, sizeof(float) * (size_t)out_size, stream);

    const size_t qkb   = (size_t)H * S * D * 2;   // 4 MiB per hi/lo array
    const size_t statb = (size_t)H * S * 4;       // 128 KiB
    const size_t base  = 4 * qkb + 2 * statb;

    int SQ = 0;
    const int cands[6] = {2048, 1024, 512, 256, 128, 64};
    for (int c = 0; c < 6; ++c) {
        size_t need = base + (size_t)H * (cands[c] + 16) * S * 2;
        if (need <= ws_size) { SQ = cands[c]; break; }
    }

    if (SQ == 0) {
        // fallback: round-2 recompute path (needs 2.25 MiB ws)
        float* mpart = (float*)d_ws;
        float* lpart = mpart + (size_t)8 * H * S;
        float* mrow  = lpart + (size_t)8 * H * S;
        float* rlrow = mrow + (size_t)H * S;
        dim3 g1(8, 128);
        fb_stats_kernel<<<g1, 256, 0, stream>>>(xq, xk, w_pre, w_psm, mpart, lpart);
        fb_reduce_kernel<<<128, 256, 0, stream>>>(mpart, lpart, mrow, rlrow);
        dim3 g2(256, 8);
        fb_out_kernel<<<g2, 256, 0, stream>>>(xq, xk, xv, w_pre, w_psm, w_post, w_posm,
                                              mrow, rlrow, out);
        return;
    }

    char* p = (char*)d_ws;
    unsigned short* qhi = (unsigned short*)p;            p += qkb;
    unsigned short* qlo = (unsigned short*)p;            p += qkb;
    unsigned short* khi = (unsigned short*)p;            p += qkb;
    unsigned short* klo = (unsigned short*)p;            p += qkb;
    float* mrow  = (float*)p;                            p += statb;
    float* rlrow = (float*)p;                            p += statb;
    unsigned short* sc = (unsigned short*)p;

    const int n8 = H * S * D / 8;
    mta_cvt_kernel<<<512, 256, 0, stream>>>(xq, qhi, qlo, SCALEQK, n8);
    mta_cvt_kernel<<<512, 256, 0, stream>>>(xk, khi, klo, 1.0f, n8);

    for (int qs = 0; qs < S; qs += SQ) {
        dim3 g1(8, SQ / 16 + 1);
        mta_score_kernel<<<g1, 256, 0, stream>>>(qhi, qlo, khi, klo, w_pre, w_psm,
                                                 sc, qs, SQ);
        mta_rowstats_kernel<<<4 * SQ, 256, 0, stream>>>(sc, mrow, rlrow, qs, SQ);
        dim3 g2(SQ / 8, 8);
        mta_out2_kernel<<<g2, 256, 0, stream>>>(sc, mrow, rlrow, xv, w_post, w_posm,
                                                out, qs, SQ);
    }
}

// Round 4
// 898.860 us; speedup vs baseline: 3.7047x; 1.7524x over previous
//
#include <hip/hip_runtime.h>
#include <math.h>

#define H 16
#define S 2048
#define D 64
#define SCALEQK 0.125f
#define CH 256

typedef __attribute__((ext_vector_type(4))) float f32x4;
typedef __attribute__((ext_vector_type(8))) short bf16x8;
typedef __attribute__((ext_vector_type(8))) _Float16 f16x8;

__device__ inline float h2f(unsigned short b) {
    _Float16 h; __builtin_memcpy(&h, &b, 2); return (float)h;
}
__device__ inline unsigned short f2h(float x) {
    _Float16 h = (_Float16)x; unsigned short b; __builtin_memcpy(&b, &h, 2); return b;
}
__device__ inline unsigned int pack2h(float a, float b) {
    return (unsigned int)f2h(a) | ((unsigned int)f2h(b) << 16);
}

// split f32 -> bf16 hi + bf16 lo (residual), rne; packed into two uint4 (8 elems)
__device__ inline void stage_hilo(float4 a, float4 b, uint4* vh, uint4* vl) {
    float xs[8] = {a.x, a.y, a.z, a.w, b.x, b.y, b.z, b.w};
    unsigned int hh[8], ll[8];
#pragma unroll
    for (int j = 0; j < 8; ++j) {
        unsigned int u = __float_as_uint(xs[j]);
        unsigned int h = (u + 0x7fffu + ((u >> 16) & 1u)) >> 16;
        float r = xs[j] - __uint_as_float(h << 16);
        unsigned int u2 = __float_as_uint(r);
        hh[j] = h;
        ll[j] = (u2 + 0x7fffu + ((u2 >> 16) & 1u)) >> 16;
    }
    uint4 h4, l4;
    h4.x = hh[0] | (hh[1] << 16); h4.y = hh[2] | (hh[3] << 16);
    h4.z = hh[4] | (hh[5] << 16); h4.w = hh[6] | (hh[7] << 16);
    l4.x = ll[0] | (ll[1] << 16); l4.y = ll[2] | (ll[3] << 16);
    l4.z = ll[4] | (ll[5] << 16); l4.w = ll[6] | (ll[7] << 16);
    *vh = h4; *vl = l4;
}

__device__ inline void online_upd(float& m, float& l, float x) {
    if (x > m) { l = l * __expf(m - x) + 1.f; m = x; }
    else       { l += __expf(x - m); }
}

// ---------------------------------------------------------------------------
// K_cvt: f32 src -> (hi, lo) bf16 split arrays, optional scale. 8 elems/thread.
__global__ __launch_bounds__(256) void mta_cvt_kernel(const float* __restrict__ src,
                                                      unsigned short* __restrict__ hi,
                                                      unsigned short* __restrict__ lo,
                                                      float scale, int n8) {
    int i = blockIdx.x * 256 + threadIdx.x;
    int stride = gridDim.x * 256;
    for (; i < n8; i += stride) {
        const float* p = src + (size_t)i * 8;
        float4 a = *(const float4*)p;
        float4 b = *(const float4*)(p + 4);
        a.x *= scale; a.y *= scale; a.z *= scale; a.w *= scale;
        b.x *= scale; b.y *= scale; b.z *= scale; b.w *= scale;
        uint4 vh, vl; stage_hilo(a, b, &vh, &vl);
        *(uint4*)&hi[(size_t)i * 8] = vh;
        *(uint4*)&lo[(size_t)i * 8] = vl;
    }
}

// K_vt: xv[f][k][d] f32 -> vt[f][d][k] f16, 64x64 LDS-tiled transpose.
__global__ __launch_bounds__(256) void mta_vt_kernel(const float* __restrict__ xv,
                                                     unsigned short* __restrict__ vt) {
    const int kt = blockIdx.x, f = blockIdx.y;
    const int tid = threadIdx.x;
    __shared__ unsigned short lt[64][65];
#pragma unroll
    for (int i = 0; i < 16; ++i) {
        int idx = tid + i * 256;
        int r = idx >> 6, c = idx & 63;
        lt[r][c] = f2h(xv[((size_t)f * S + kt * 64 + r) * D + c]);
    }
    __syncthreads();
#pragma unroll
    for (int i = 0; i < 16; ++i) {
        int idx = tid + i * 256;
        int d = idx >> 6, k = idx & 63;
        vt[((size_t)f * D + d) * S + kt * 64 + k] = lt[k][d];
    }
}

// ---------------------------------------------------------------------------
// Pass 1: mixed scores (QK^T split-bf16 MFMA + 6x11 causal conv + w_psm mix)
// written as f16 to the stripe score buffer. 16 q rows x 256-k chunk per block.
__global__ __launch_bounds__(256) void mta_score_kernel(
        const unsigned short* __restrict__ qhi, const unsigned short* __restrict__ qlo,
        const unsigned short* __restrict__ khi, const unsigned short* __restrict__ klo,
        const float* __restrict__ w_pre, const float* __restrict__ w_psm,
        unsigned short* __restrict__ sc, int qs, int SQ) {
    const int kc = blockIdx.x, qt = blockIdx.y;
    const int q0 = qs - 16 + qt * 16;          // tile 0 is the halo tile
    const int kstart = kc * CH;
    if (kstart > q0 + 15) return;
    const int kend = min(kstart + CH, q0 + 16);
    const int tid = threadIdx.x;

    __shared__ unsigned short Qs[2][2][32][72];  // [buf][hi/lo][row][col]
    __shared__ unsigned short Ks[2][2][48][72];
    __shared__ float raws[2][32][48];
    __shared__ float wpre_s[16 * 66];
    __shared__ float wpsm_s[256];

    for (int i = tid; i < 16 * 66; i += 256) wpre_s[i] = w_pre[i];
    wpsm_s[tid] = w_psm[tid];

    const int ql = tid >> 4;          // 0..15
    const int kb = (tid & 15) * 2;    // 0..30
    const int q = q0 + ql;
    const int rowl = q - (qs - 16);   // local buffer row

#define STAGE1(hh, bb) do { \
        int r_ = tid >> 3, d_ = (tid & 7) * 8; \
        int qp_ = q0 - 5 + r_; \
        uint4 vh_ = {0,0,0,0}, vl_ = {0,0,0,0}; \
        if (r_ < 21 && qp_ >= 0) { \
            size_t off_ = ((size_t)(hh) * S + qp_) * D + d_; \
            vh_ = *(const uint4*)&qhi[off_]; vl_ = *(const uint4*)&qlo[off_]; } \
        *(uint4*)&Qs[bb][0][r_][d_] = vh_; *(uint4*)&Qs[bb][1][r_][d_] = vl_; \
        for (int i_ = tid; i_ < 384; i_ += 256) { \
            int rr_ = i_ >> 3, dd_ = (i_ & 7) * 8; \
            int kp_ = k0 - 10 + rr_; \
            uint4 wh_ = {0,0,0,0}, wl_ = {0,0,0,0}; \
            if (rr_ < 42 && kp_ >= 0 && kp_ < S) { \
                size_t off_ = ((size_t)(hh) * S + kp_) * D + dd_; \
                wh_ = *(const uint4*)&khi[off_]; wl_ = *(const uint4*)&klo[off_]; } \
            *(uint4*)&Ks[bb][0][rr_][dd_] = wh_; *(uint4*)&Ks[bb][1][rr_][dd_] = wl_; } \
    } while (0)

#define MFMA1(bb) do { \
        int w_ = tid >> 6, l_ = tid & 63; \
        int lr_ = l_ & 15, lk_ = l_ >> 4; \
        for (int t_ = w_; t_ < 6; t_ += 4) { \
            int tr_ = t_ / 3, tc_ = t_ % 3; \
            f32x4 acc_ = {0.f, 0.f, 0.f, 0.f}; \
            _Pragma("unroll") \
            for (int ks_ = 0; ks_ < 2; ++ks_) { \
                int db_ = ks_ * 32 + lk_ * 8; \
                bf16x8 ah_ = *(const bf16x8*)&Qs[bb][0][tr_ * 16 + lr_][db_]; \
                bf16x8 al_ = *(const bf16x8*)&Qs[bb][1][tr_ * 16 + lr_][db_]; \
                bf16x8 bh_ = *(const bf16x8*)&Ks[bb][0][tc_ * 16 + lr_][db_]; \
                bf16x8 bl_ = *(const bf16x8*)&Ks[bb][1][tc_ * 16 + lr_][db_]; \
                acc_ = __builtin_amdgcn_mfma_f32_16x16x32_bf16(ah_, bh_, acc_, 0, 0, 0); \
                acc_ = __builtin_amdgcn_mfma_f32_16x16x32_bf16(ah_, bl_, acc_, 0, 0, 0); \
                acc_ = __builtin_amdgcn_mfma_f32_16x16x32_bf16(al_, bh_, acc_, 0, 0, 0); \
            } \
            _Pragma("unroll") \
            for (int i_ = 0; i_ < 4; ++i_) { \
                int row_ = tr_ * 16 + lk_ * 4 + i_, col_ = tc_ * 16 + lr_; \
                int qp_ = q0 - 5 + row_, kp_ = k0 - 10 + col_; \
                raws[bb][row_][col_] = (kp_ >= 0 && kp_ <= qp_) ? acc_[i_] : 0.f; \
            } \
        } \
    } while (0)

#define CONV1(hc, bb) do { \
        float c0_ = 0.f, c1_ = 0.f; \
        _Pragma("unroll") \
        for (int i2_ = 0; i2_ < 6; ++i2_) { \
            const float* rp_ = &raws[bb][ql + i2_][kb]; \
            float v_[12]; \
            _Pragma("unroll") \
            for (int j_ = 0; j_ < 6; ++j_) { \
                float2 t_ = *(const float2*)(rp_ + 2 * j_); \
                v_[2 * j_] = t_.x; v_[2 * j_ + 1] = t_.y; } \
            const float* wp_ = &wpre_s[(hc) * 66 + i2_ * 11]; \
            _Pragma("unroll") \
            for (int j_ = 0; j_ < 11; ++j_) { c0_ += wp_[j_] * v_[j_]; c1_ += wp_[j_] * v_[j_ + 1]; } \
        } \
        _Pragma("unroll") \
        for (int g_ = 0; g_ < 16; ++g_) { \
            float wg_ = wpsm_s[g_ * 16 + (hc)]; \
            acc0[g_] += wg_ * c0_; acc1[g_] += wg_ * c1_; \
        } \
    } while (0)

    for (int k0 = kstart; k0 < kend; k0 += 32) {
        float acc0[16], acc1[16];
#pragma unroll
        for (int g = 0; g < 16; ++g) { acc0[g] = 0.f; acc1[g] = 0.f; }

        STAGE1(0, 0);
        __syncthreads();
        for (int h = 0; h < 16; ++h) {
            MFMA1(h & 1);
            if (h < 15) STAGE1(h + 1, (h + 1) & 1);
            if (h > 0) CONV1(h - 1, (h - 1) & 1);
            __syncthreads();
        }
        CONV1(15, 1);

        // write f16 scores (0 above diagonal; never read there)
        int kk = k0 + kb;
#pragma unroll
        for (int g = 0; g < 16; ++g) {
            unsigned int pack = pack2h((kk <= q) ? acc0[g] : 0.f,
                                       (kk + 1 <= q) ? acc1[g] : 0.f);
            *(unsigned int*)&sc[((size_t)(g * (SQ + 16) + rowl)) * S + kk] = pack;
        }
        __syncthreads();  // raws/Qs reuse next k-step
    }
#undef STAGE1
#undef MFMA1
#undef CONV1
}

// ---------------------------------------------------------------------------
// Stats: per (g,q) row of the stripe, m = max, l = sum exp(x-m) over k<=q.
__global__ __launch_bounds__(256) void mta_rowstats_kernel(
        const unsigned short* __restrict__ sc,
        float* __restrict__ mrow, float* __restrict__ rlrow, int qs, int SQ) {
    int row = blockIdx.x * 4 + (threadIdx.x >> 6);
    int lane = threadIdx.x & 63;
    int g = row / SQ, qq = row % SQ;
    int q = qs + qq;
    const unsigned short* rp = sc + ((size_t)(g * (SQ + 16) + qq + 16)) * S;

    float v[32];
#pragma unroll
    for (int it = 0; it < 4; ++it) {
        int kbase = it * 512 + lane * 8;
        if (it * 512 <= q) {
            uint4 u = *(const uint4*)&rp[kbase];
            unsigned int ws[4] = {u.x, u.y, u.z, u.w};
#pragma unroll
            for (int j = 0; j < 4; ++j) {
                float x0 = h2f((unsigned short)(ws[j] & 0xffff));
                float x1 = h2f((unsigned short)(ws[j] >> 16));
                v[it * 8 + 2 * j]     = (kbase + 2 * j     <= q) ? x0 : -INFINITY;
                v[it * 8 + 2 * j + 1] = (kbase + 2 * j + 1 <= q) ? x1 : -INFINITY;
            }
        } else {
#pragma unroll
            for (int j = 0; j < 8; ++j) v[it * 8 + j] = -INFINITY;
        }
    }
    float m = -INFINITY;
#pragma unroll
    for (int j = 0; j < 32; ++j) m = fmaxf(m, v[j]);
#pragma unroll
    for (int off = 1; off < 64; off <<= 1) m = fmaxf(m, __shfl_xor(m, off));
    float l = 0.f;
#pragma unroll
    for (int j = 0; j < 32; ++j) l += __expf(v[j] - m);
#pragma unroll
    for (int off = 1; off < 64; off <<= 1) l += __shfl_xor(l, off);
    if (lane == 0) { mrow[g * S + q] = m; rlrow[g * S + q] = 1.f / l; }
}

// ---------------------------------------------------------------------------
// Pass 2: probs = exp(sc - m)/l, 3x3 causal conv, w_posm mix, MFMA PV.
// 16 q rows x 256-k chunk per block; accumulate PV in VGPRs, atomicAdd once.
__global__ __launch_bounds__(256) void mta_out2_kernel(
        const unsigned short* __restrict__ sc,
        const float* __restrict__ mrow, const float* __restrict__ rlrow,
        const unsigned short* __restrict__ vt,
        const float* __restrict__ w_post, const float* __restrict__ w_posm,
        float* __restrict__ out, int qs, int SQ) {
    const int qt = blockIdx.x, kc = blockIdx.y;
    const int q0 = qs + qt * 16;
    const int kstart = kc * CH;
    if (kstart > q0 + 15) return;
    const int kend = min(kstart + CH, q0 + 16);
    const int tid = threadIdx.x;

    __shared__ unsigned short ps[16][18][36];   // probs f16, rows q0-2..q0+15, cols k0-2..k0+31
    __shared__ unsigned short pm2[16][16][40];  // mixed probs f16 (stride 40 -> 16B-aligned rows)
    __shared__ float mst[16][18], rst[16][18];
    __shared__ float wpost_s[144], wposm_s[256];

    wposm_s[tid] = w_posm[tid];
    if (tid < 144) wpost_s[tid] = w_post[tid];
    for (int i = tid; i < 288; i += 256) {
        int g = i / 18, r = i % 18;
        int qp = q0 - 2 + r;
        if (qp >= 0) { mst[g][r] = mrow[g * S + qp]; rst[g][r] = rlrow[g * S + qp]; }
        else         { mst[g][r] = 0.f; rst[g][r] = 0.f; }
    }

    const int ql = tid >> 4, kb = (tid & 15) * 2;   // conv/mix mapping
    const int wv = tid >> 6, lane = tid & 63;
    const int lr = lane & 15, lk = lane >> 4;

    f32x4 acc[4][4];   // [head-within-wave][d-tile]
#pragma unroll
    for (int a = 0; a < 4; ++a)
#pragma unroll
        for (int b = 0; b < 4; ++b) acc[a][b] = (f32x4){0.f, 0.f, 0.f, 0.f};

    __syncthreads();   // mst/weights ready

    for (int k0 = kstart; k0 < kend; k0 += 32) {
        // stage normalized probs as f16: 16g x 18r x 17 uint-pairs
        for (int i = tid; i < 4896; i += 256) {
            int g = i / 306, rem = i % 306;
            int r = rem / 17, c2 = (rem % 17) * 2;
            int qp = q0 - 2 + r;
            int kp = k0 - 2 + c2;
            float p0 = 0.f, p1 = 0.f;
            if (qp >= 0 && kp >= 0) {
                unsigned int u = *(const unsigned int*)
                    &sc[((size_t)(g * (SQ + 16) + qp - (qs - 16))) * S + kp];
                float mm = mst[g][r], rr = rst[g][r];
                if (kp <= qp)     p0 = __expf(h2f((unsigned short)(u & 0xffff)) - mm) * rr;
                if (kp + 1 <= qp) p1 = __expf(h2f((unsigned short)(u >> 16)) - mm) * rr;
            }
            *(unsigned int*)&ps[g][r][c2] = pack2h(p0, p1);
        }
        __syncthreads();  // barA: ps ready; also protects pm2 (prev MFMA reads done)

        // 3x3 conv + w_posm mix for 2 adjacent k per thread -> pm2 f16
        {
            float cg0[16], cg1[16];
#pragma unroll
            for (int g = 0; g < 16; ++g) {
                float c0 = 0.f, c1 = 0.f;
#pragma unroll
                for (int i2 = 0; i2 < 3; ++i2) {
                    unsigned int u0 = *(const unsigned int*)&ps[g][ql + i2][kb];
                    unsigned int u1 = *(const unsigned int*)&ps[g][ql + i2][kb + 2];
                    float v0 = h2f((unsigned short)(u0 & 0xffff));
                    float v1 = h2f((unsigned short)(u0 >> 16));
                    float v2 = h2f((unsigned short)(u1 & 0xffff));
                    float v3 = h2f((unsigned short)(u1 >> 16));
                    const float* wp = &wpost_s[g * 9 + i2 * 3];
                    c0 += wp[0] * v0 + wp[1] * v1 + wp[2] * v2;
                    c1 += wp[0] * v1 + wp[1] * v2 + wp[2] * v3;
                }
                cg0[g] = c0; cg1[g] = c1;
            }
            int q = q0 + ql, k = k0 + kb;
            bool val0 = (k <= q) && (k < kend);
            bool val1 = (k + 1 <= q) && (k + 1 < kend);
#pragma unroll
            for (int ff = 0; ff < 16; ++ff) {
                float s0 = 0.f, s1 = 0.f;
#pragma unroll
                for (int g = 0; g < 16; ++g) {
                    float w = wposm_s[ff * 16 + g];
                    s0 += w * cg0[g]; s1 += w * cg1[g];
                }
                *(unsigned int*)&pm2[ff][ql][kb] = pack2h(val0 ? s0 : 0.f, val1 ? s1 : 0.f);
            }
        }
        __syncthreads();  // barB: pm2 ready

        // MFMA PV: wave wv handles heads wv*4..wv*4+3; B-frags direct from global vt
#pragma unroll
        for (int hh = 0; hh < 4; ++hh) {
            int f = wv * 4 + hh;
            f16x8 a = *(const f16x8*)&pm2[f][lr][lk * 8];
#pragma unroll
            for (int tc = 0; tc < 4; ++tc) {
                uint4 braw = *(const uint4*)
                    &vt[((size_t)(f * D + tc * 16 + lr)) * S + k0 + lk * 8];
                f16x8 b;
                __builtin_memcpy(&b, &braw, 16);
                acc[hh][tc] = __builtin_amdgcn_mfma_f32_16x16x32_f16(a, b, acc[hh][tc], 0, 0, 0);
            }
        }
        // next iteration's barA orders MFMA pm2-reads vs next conv writes
    }

    // epilogue: one atomicAdd pass
#pragma unroll
    for (int hh = 0; hh < 4; ++hh) {
        int f = wv * 4 + hh;
#pragma unroll
        for (int tc = 0; tc < 4; ++tc) {
#pragma unroll
            for (int i = 0; i < 4; ++i) {
                int q = q0 + lk * 4 + i;
                int d = tc * 16 + lr;
                atomicAdd(&out[((size_t)q * H + f) * D + d], acc[hh][tc][i]);
            }
        }
    }
}

// ===========================================================================
// Fallback path (round-2 kernels, verbatim): used when ws_size is too small.
// ===========================================================================
__global__ __launch_bounds__(256) void fb_stats_kernel(
        const float* __restrict__ xq, const float* __restrict__ xk,
        const float* __restrict__ w_pre, const float* __restrict__ w_psm,
        float* __restrict__ mpart, float* __restrict__ lpart) {
    const int kc = blockIdx.x, qt = blockIdx.y;
    const int q0 = qt * 16;
    const int kstart = kc * CH;
    if (kstart > q0 + 15) return;
    const int kend = min(kstart + CH, q0 + 16);
    const int tid = threadIdx.x;

    __shared__ unsigned short Qs[2][32][72];
    __shared__ unsigned short Ks[2][48][72];
    __shared__ float raws[32][50];
    __shared__ float wpre_s[16 * 66];
    __shared__ float wpsm_s[256];

    for (int i = tid; i < 16 * 66; i += 256) wpre_s[i] = w_pre[i];
    wpsm_s[tid] = w_psm[tid];

    const int ql = tid >> 4;
    const int kb = (tid & 15) * 2;
    const int q = q0 + ql;

    float mreg[16], lreg[16];
#pragma unroll
    for (int g = 0; g < 16; ++g) { mreg[g] = -INFINITY; lreg[g] = 0.f; }

    for (int k0 = kstart; k0 < kend; k0 += 32) {
        float acc0[16], acc1[16];
#pragma unroll
        for (int g = 0; g < 16; ++g) { acc0[g] = 0.f; acc1[g] = 0.f; }

        for (int h = 0; h < H; ++h) {
            {
                int r = tid >> 3, d = (tid & 7) * 8;
                int qp = q0 - 5 + r;
                float4 a = {0,0,0,0}, b = {0,0,0,0};
                if (r < 21 && qp >= 0) {
                    const float* p = &xq[(h * S + qp) * D + d];
                    a = *(const float4*)p; b = *(const float4*)(p + 4);
                }
                uint4 vh, vl; stage_hilo(a, b, &vh, &vl);
                *(uint4*)&Qs[0][r][d] = vh;
                *(uint4*)&Qs[1][r][d] = vl;
            }
            for (int i = tid; i < 384; i += 256) {
                int r = i >> 3, d = (i & 7) * 8;
                int kp = k0 - 10 + r;
                float4 a = {0,0,0,0}, b = {0,0,0,0};
                if (r < 42 && kp >= 0) {
                    const float* p = &xk[(h * S + kp) * D + d];
                    a = *(const float4*)p; b = *(const float4*)(p + 4);
                }
                uint4 vh, vl; stage_hilo(a, b, &vh, &vl);
                *(uint4*)&Ks[0][r][d] = vh;
                *(uint4*)&Ks[1][r][d] = vl;
            }
            __syncthreads();
            {
                int w = tid >> 6, l = tid & 63;
                int lr = l & 15, lk = l >> 4;
                for (int t = w; t < 6; t += 4) {
                    int tr = t / 3, tc = t % 3;
                    f32x4 acc = {0.f, 0.f, 0.f, 0.f};
#pragma unroll
                    for (int ks = 0; ks < 2; ++ks) {
                        int db = ks * 32 + lk * 8;
                        bf16x8 ah = *(const bf16x8*)&Qs[0][tr * 16 + lr][db];
                        bf16x8 al = *(const bf16x8*)&Qs[1][tr * 16 + lr][db];
                        bf16x8 bh = *(const bf16x8*)&Ks[0][tc * 16 + lr][db];
                        bf16x8 bl = *(const bf16x8*)&Ks[1][tc * 16 + lr][db];
                        acc = __builtin_amdgcn_mfma_f32_16x16x32_bf16(ah, bh, acc, 0, 0, 0);
                        acc = __builtin_amdgcn_mfma_f32_16x16x32_bf16(ah, bl, acc, 0, 0, 0);
                        acc = __builtin_amdgcn_mfma_f32_16x16x32_bf16(al, bh, acc, 0, 0, 0);
                    }
#pragma unroll
                    for (int i = 0; i < 4; ++i) {
                        int row = tr * 16 + lk * 4 + i;
                        int col = tc * 16 + lr;
                        int qp = q0 - 5 + row, kp = k0 - 10 + col;
                        raws[row][col] = (kp >= 0 && kp <= qp) ? acc[i] * SCALEQK : 0.f;
                    }
                }
            }
            __syncthreads();
            {
                float c0 = 0.f, c1 = 0.f;
#pragma unroll
                for (int i2 = 0; i2 < 6; ++i2) {
                    const float* rp = &raws[ql + i2][kb];
                    float v[12];
#pragma unroll
                    for (int j = 0; j < 6; ++j) {
                        float2 t = *(const float2*)(rp + 2 * j);
                        v[2 * j] = t.x; v[2 * j + 1] = t.y;
                    }
                    const float* wp = &wpre_s[h * 66 + i2 * 11];
#pragma unroll
                    for (int j = 0; j < 11; ++j) { c0 += wp[j] * v[j]; c1 += wp[j] * v[j + 1]; }
                }
#pragma unroll
                for (int g = 0; g < 16; ++g) {
                    float wg = wpsm_s[g * 16 + h];
                    acc0[g] += wg * c0; acc1[g] += wg * c1;
                }
            }
        }
        int kk = k0 + kb;
#pragma unroll
        for (int g = 0; g < 16; ++g) {
            if (kk <= q)     online_upd(mreg[g], lreg[g], acc0[g]);
            if (kk + 1 <= q) online_upd(mreg[g], lreg[g], acc1[g]);
        }
    }
#pragma unroll
    for (int g = 0; g < 16; ++g) {
        float m = mreg[g], l = lreg[g];
#pragma unroll
        for (int off = 1; off < 16; off <<= 1) {
            float m2 = __shfl_xor(m, off);
            float l2 = __shfl_xor(l, off);
            float nm = fmaxf(m, m2);
            float t1 = (l  > 0.f) ? l  * __expf(m  - nm) : 0.f;
            float t2 = (l2 > 0.f) ? l2 * __expf(m2 - nm) : 0.f;
            m = nm; l = t1 + t2;
        }
        if ((tid & 15) == 0) {
            mpart[((size_t)kc * H + g) * S + q] = m;
            lpart[((size_t)kc * H + g) * S + q] = l;
        }
    }
}

__global__ __launch_bounds__(256) void fb_reduce_kernel(
        const float* __restrict__ mpart, const float* __restrict__ lpart,
        float* __restrict__ mrow, float* __restrict__ rlrow) {
    int r = blockIdx.x * 256 + threadIdx.x;
    if (r >= H * S) return;
    int q = r & (S - 1);
    int nkc = (q >> 8) + 1;
    float m = -INFINITY;
    for (int kc = 0; kc < nkc; ++kc) m = fmaxf(m, mpart[(size_t)kc * H * S + r]);
    float l = 0.f;
    for (int kc = 0; kc < nkc; ++kc) {
        float li = lpart[(size_t)kc * H * S + r];
        float mi = mpart[(size_t)kc * H * S + r];
        if (li > 0.f) l += li * __expf(mi - m);
    }
    mrow[r] = m;
    rlrow[r] = 1.f / l;
}

__global__ __launch_bounds__(256) void fb_out_kernel(
        const float* __restrict__ xq, const float* __restrict__ xk,
        const float* __restrict__ xv,
        const float* __restrict__ w_pre, const float* __restrict__ w_psm,
        const float* __restrict__ w_post, const float* __restrict__ w_posm,
        const float* __restrict__ mrow, const float* __restrict__ rlrow,
        float* __restrict__ out) {
    const int qt = blockIdx.x, kc = blockIdx.y;
    const int q0 = qt * 8;
    const int kstart = kc * CH;
    if (kstart > q0 + 7) return;
    const int kend = min(kstart + CH, q0 + 8);
    const int tid = threadIdx.x;

    __shared__ unsigned short Qs[2][16][72];
    __shared__ unsigned short Ks[2][48][72];
    __shared__ float raws[16][50];
    __shared__ float ps[8][10][35];
    __shared__ float m2s[16][8][33];
    __shared__ float mst[16][10], rst[16][10];
    __shared__ float wpre_s[16 * 66], wpsm_s[256], wpost_s[144], wposm_s[256];

    for (int i = tid; i < 16 * 66; i += 256) wpre_s[i] = w_pre[i];
    wpsm_s[tid] = w_psm[tid];
    wposm_s[tid] = w_posm[tid];
    if (tid < 144) wpost_s[tid] = w_post[tid];
    for (int i = tid; i < 160; i += 256) {
        int g = i / 10, r = i % 10;
        int qp = q0 - 2 + r;
        if (qp >= 0) { mst[g][r] = mrow[g * S + qp]; rst[g][r] = rlrow[g * S + qp]; }
        else         { mst[g][r] = 0.f; rst[g][r] = 0.f; }
    }

    const int f = tid >> 4, qloc = (tid >> 1) & 7, dh = tid & 1;
    const int cr = tid / 17, cc = (tid % 17) * 2;
    const bool cvalid = tid < 170;
    const int ql2 = tid >> 5, kl = tid & 31;

    float oacc[32];
#pragma unroll
    for (int i = 0; i < 32; ++i) oacc[i] = 0.f;

    for (int k0 = kstart; k0 < kend; k0 += 32) {
        float a0[16], a1[16];
#pragma unroll
        for (int g = 0; g < 16; ++g) { a0[g] = 0.f; a1[g] = 0.f; }

        for (int h = 0; h < H; ++h) {
            if (tid < 128) {
                int r = tid >> 3, d = (tid & 7) * 8;
                int qp = q0 - 7 + r;
                float4 a = {0,0,0,0}, b = {0,0,0,0};
                if (qp >= 0 && qp < S) {
                    const float* p = &xq[(h * S + qp) * D + d];
                    a = *(const float4*)p; b = *(const float4*)(p + 4);
                }
                uint4 vh, vl; stage_hilo(a, b, &vh, &vl);
                *(uint4*)&Qs[0][r][d] = vh;
                *(uint4*)&Qs[1][r][d] = vl;
            }
            for (int i = tid; i < 384; i += 256) {
                int r = i >> 3, d = (i & 7) * 8;
                int kp = k0 - 12 + r;
                float4 a = {0,0,0,0}, b = {0,0,0,0};
                if (kp >= 0 && kp < S) {
                    const float* p = &xk[(h * S + kp) * D + d];
                    a = *(const float4*)p; b = *(const float4*)(p + 4);
                }
                uint4 vh, vl; stage_hilo(a, b, &vh, &vl);
                *(uint4*)&Ks[0][r][d] = vh;
                *(uint4*)&Ks[1][r][d] = vl;
            }
            __syncthreads();
            {
                int w = tid >> 6, l = tid & 63;
                int lr = l & 15, lk = l >> 4;
                if (w < 3) {
                    int tc = w;
                    f32x4 acc = {0.f, 0.f, 0.f, 0.f};
#pragma unroll
                    for (int ks = 0; ks < 2; ++ks) {
                        int db = ks * 32 + lk * 8;
                        bf16x8 ah = *(const bf16x8*)&Qs[0][lr][db];
                        bf16x8 al = *(const bf16x8*)&Qs[1][lr][db];
                        bf16x8 bh = *(const bf16x8*)&Ks[0][tc * 16 + lr][db];
                        bf16x8 bl = *(const bf16x8*)&Ks[1][tc * 16 + lr][db];
                        acc = __builtin_amdgcn_mfma_f32_16x16x32_bf16(ah, bh, acc, 0, 0, 0);
                        acc = __builtin_amdgcn_mfma_f32_16x16x32_bf16(ah, bl, acc, 0, 0, 0);
                        acc = __builtin_amdgcn_mfma_f32_16x16x32_bf16(al, bh, acc, 0, 0, 0);
                    }
#pragma unroll
                    for (int i = 0; i < 4; ++i) {
                        int row = lk * 4 + i, col = tc * 16 + lr;
                        int qp = q0 - 7 + row, kp = k0 - 12 + col;
                        raws[row][col] = (kp >= 0 && kp <= qp) ? acc[i] * SCALEQK : 0.f;
                    }
                }
            }
            __syncthreads();
            if (cvalid) {
                float c0 = 0.f, c1 = 0.f;
#pragma unroll
                for (int i2 = 0; i2 < 6; ++i2) {
                    const float* rp = &raws[cr + i2][cc];
                    float v[12];
#pragma unroll
                    for (int j = 0; j < 6; ++j) {
                        float2 t = *(const float2*)(rp + 2 * j);
                        v[2 * j] = t.x; v[2 * j + 1] = t.y;
                    }
                    const float* wp = &wpre_s[h * 66 + i2 * 11];
#pragma unroll
                    for (int j = 0; j < 11; ++j) { c0 += wp[j] * v[j]; c1 += wp[j] * v[j + 1]; }
                }
#pragma unroll
                for (int g = 0; g < 16; ++g) {
                    float wg = wpsm_s[g * 16 + h];
                    a0[g] += wg * c0; a1[g] += wg * c1;
                }
            }
        }

        float m2f[16];
#pragma unroll
        for (int i = 0; i < 16; ++i) m2f[i] = 0.f;

        for (int half = 0; half < 2; ++half) {
            if (cvalid) {
                int qp = q0 - 2 + cr;
                int kp0 = k0 - 2 + cc, kp1 = kp0 + 1;
#pragma unroll
                for (int g8 = 0; g8 < 8; ++g8) {
                    int g = half * 8 + g8;
                    float p0 = 0.f, p1 = 0.f;
                    if (qp >= 0) {
                        float mm = mst[g][cr], rr = rst[g][cr];
                        if (kp0 >= 0 && kp0 <= qp) p0 = __expf(a0[g] - mm) * rr;
                        if (kp1 >= 0 && kp1 <= qp) p1 = __expf(a1[g] - mm) * rr;
                    }
                    ps[g8][cr][cc] = p0;
                    ps[g8][cr][cc + 1] = p1;
                }
            }
            __syncthreads();
            {
                float cg[8];
#pragma unroll
                for (int g8 = 0; g8 < 8; ++g8) {
                    float c = 0.f;
#pragma unroll
                    for (int i2 = 0; i2 < 3; ++i2)
#pragma unroll
                        for (int j2 = 0; j2 < 3; ++j2)
                            c += wpost_s[(half * 8 + g8) * 9 + i2 * 3 + j2] * ps[g8][ql2 + i2][kl + j2];
                    cg[g8] = c;
                }
#pragma unroll
                for (int ff = 0; ff < 16; ++ff) {
                    float s = 0.f;
#pragma unroll
                    for (int g8 = 0; g8 < 8; ++g8) s += wposm_s[ff * 16 + half * 8 + g8] * cg[g8];
                    m2f[ff] += s;
                }
            }
            if (half == 0) __syncthreads();
        }
        {
            int q = q0 + ql2, k = k0 + kl;
            bool valid = (k <= q) && (k < kend);
#pragma unroll
            for (int ff = 0; ff < 16; ++ff) m2s[ff][ql2][kl] = valid ? m2f[ff] : 0.f;
        }
        __syncthreads();
        for (int kl2 = 0; kl2 < 32; ++kl2) {
            int k = k0 + kl2;
            if (k >= kend) break;
            float s = m2s[f][qloc][kl2];
            if (s != 0.f) {
                const float* vp = &xv[(f * S + k) * D + dh * 32];
#pragma unroll
                for (int d4 = 0; d4 < 8; ++d4) {
                    float4 v = *(const float4*)(vp + d4 * 4);
                    oacc[d4 * 4 + 0] += s * v.x;
                    oacc[d4 * 4 + 1] += s * v.y;
                    oacc[d4 * 4 + 2] += s * v.z;
                    oacc[d4 * 4 + 3] += s * v.w;
                }
            }
        }
        __syncthreads();
    }

    int q = q0 + qloc;
    float* op = out + ((size_t)q * H + f) * D + dh * 32;
#pragma unroll
    for (int i = 0; i < 32; ++i) atomicAdd(op + i, oacc[i]);
}

// ===========================================================================
extern "C" void kernel_launch(void* const* d_in, const int* in_sizes, int n_in,
                              void* d_out, int out_size, void* d_ws, size_t ws_size,
                              hipStream_t stream) {
    const float* xq     = (const float*)d_in[0];
    const float* xk     = (const float*)d_in[1];
    const float* xv     = (const float*)d_in[2];
    const float* w_pre  = (const float*)d_in[4];
    const float* w_post = (const float*)d_in[5];
    const float* w_psm  = (const float*)d_in[6];
    const float* w_posm = (const float*)d_in[7];
    float* out = (float*)d_out;

    hipMemsetAsync(d_out, 0, sizeof(float) * (size_t)out_size, stream);

    const size_t qkb   = (size_t)H * S * D * 2;   // 4 MiB per hi/lo array
    const size_t vtb   = (size_t)H * D * S * 2;   // 4 MiB
    const size_t statb = (size_t)H * S * 4;       // 128 KiB
    const size_t base  = 4 * qkb + vtb + 2 * statb;

    int SQ = 0;
    const int cands[6] = {2048, 1024, 512, 256, 128, 64};
    for (int c = 0; c < 6; ++c) {
        size_t need = base + (size_t)H * (cands[c] + 16) * S * 2;
        if (need <= ws_size) { SQ = cands[c]; break; }
    }

    if (SQ == 0) {
        float* mpart = (float*)d_ws;
        float* lpart = mpart + (size_t)8 * H * S;
        float* mrow  = lpart + (size_t)8 * H * S;
        float* rlrow = mrow + (size_t)H * S;
        dim3 g1(8, 128);
        fb_stats_kernel<<<g1, 256, 0, stream>>>(xq, xk, w_pre, w_psm, mpart, lpart);
        fb_reduce_kernel<<<128, 256, 0, stream>>>(mpart, lpart, mrow, rlrow);
        dim3 g2(256, 8);
        fb_out_kernel<<<g2, 256, 0, stream>>>(xq, xk, xv, w_pre, w_psm, w_post, w_posm,
                                              mrow, rlrow, out);
        return;
    }

    char* p = (char*)d_ws;
    unsigned short* qhi = (unsigned short*)p;            p += qkb;
    unsigned short* qlo = (unsigned short*)p;            p += qkb;
    unsigned short* khi = (unsigned short*)p;            p += qkb;
    unsigned short* klo = (unsigned short*)p;            p += qkb;
    unsigned short* vt  = (unsigned short*)p;            p += vtb;
    float* mrow  = (float*)p;                            p += statb;
    float* rlrow = (float*)p;                            p += statb;
    unsigned short* sc = (unsigned short*)p;

    const int n8 = H * S * D / 8;
    mta_cvt_kernel<<<512, 256, 0, stream>>>(xq, qhi, qlo, SCALEQK, n8);
    mta_cvt_kernel<<<512, 256, 0, stream>>>(xk, khi, klo, 1.0f, n8);
    dim3 gv(S / 64, H);
    mta_vt_kernel<<<gv, 256, 0, stream>>>(xv, vt);

    for (int qs = 0; qs < S; qs += SQ) {
        dim3 g1(8, SQ / 16 + 1);
        mta_score_kernel<<<g1, 256, 0, stream>>>(qhi, qlo, khi, klo, w_pre, w_psm,
                                                 sc, qs, SQ);
        mta_rowstats_kernel<<<4 * SQ, 256, 0, stream>>>(sc, mrow, rlrow, qs, SQ);
        dim3 g2(SQ / 16, 8);
        mta_out2_kernel<<<g2, 256, 0, stream>>>(sc, mrow, rlrow, vt, w_post, w_posm,
                                                out, qs, SQ);
    }
}

// Round 5
// 659.012 us; speedup vs baseline: 5.0531x; 1.3640x over previous
//
#include <hip/hip_runtime.h>
#include <math.h>

#define H 16
#define S 2048
#define D 64
#define SCALEQK 0.125f
#define CH 256

typedef __attribute__((ext_vector_type(4))) float f32x4;
typedef __attribute__((ext_vector_type(8))) short bf16x8;
typedef __attribute__((ext_vector_type(8))) _Float16 f16x8;

__device__ inline float h2f(unsigned short b) {
    _Float16 h; __builtin_memcpy(&h, &b, 2); return (float)h;
}
__device__ inline unsigned short f2h(float x) {
    _Float16 h = (_Float16)x; unsigned short b; __builtin_memcpy(&b, &h, 2); return b;
}
__device__ inline unsigned int pack2h(float a, float b) {
    return (unsigned int)f2h(a) | ((unsigned int)f2h(b) << 16);
}

// split f32 -> bf16 hi + bf16 lo (residual), rne; packed into two uint4 (8 elems)
__device__ inline void stage_hilo(float4 a, float4 b, uint4* vh, uint4* vl) {
    float xs[8] = {a.x, a.y, a.z, a.w, b.x, b.y, b.z, b.w};
    unsigned int hh[8], ll[8];
#pragma unroll
    for (int j = 0; j < 8; ++j) {
        unsigned int u = __float_as_uint(xs[j]);
        unsigned int h = (u + 0x7fffu + ((u >> 16) & 1u)) >> 16;
        float r = xs[j] - __uint_as_float(h << 16);
        unsigned int u2 = __float_as_uint(r);
        hh[j] = h;
        ll[j] = (u2 + 0x7fffu + ((u2 >> 16) & 1u)) >> 16;
    }
    uint4 h4, l4;
    h4.x = hh[0] | (hh[1] << 16); h4.y = hh[2] | (hh[3] << 16);
    h4.z = hh[4] | (hh[5] << 16); h4.w = hh[6] | (hh[7] << 16);
    l4.x = ll[0] | (ll[1] << 16); l4.y = ll[2] | (ll[3] << 16);
    l4.z = ll[4] | (ll[5] << 16); l4.w = ll[6] | (ll[7] << 16);
    *vh = h4; *vl = l4;
}

__device__ inline void online_upd(float& m, float& l, float x) {
    if (x > m) { l = l * __expf(m - x) + 1.f; m = x; }
    else       { l += __expf(x - m); }
}

// ---------------------------------------------------------------------------
// K_cvt: f32 src -> (hi, lo) bf16 split arrays, optional scale. 8 elems/thread.
__global__ __launch_bounds__(256) void mta_cvt_kernel(const float* __restrict__ src,
                                                      unsigned short* __restrict__ hi,
                                                      unsigned short* __restrict__ lo,
                                                      float scale, int n8) {
    int i = blockIdx.x * 256 + threadIdx.x;
    int stride = gridDim.x * 256;
    for (; i < n8; i += stride) {
        const float* p = src + (size_t)i * 8;
        float4 a = *(const float4*)p;
        float4 b = *(const float4*)(p + 4);
        a.x *= scale; a.y *= scale; a.z *= scale; a.w *= scale;
        b.x *= scale; b.y *= scale; b.z *= scale; b.w *= scale;
        uint4 vh, vl; stage_hilo(a, b, &vh, &vl);
        *(uint4*)&hi[(size_t)i * 8] = vh;
        *(uint4*)&lo[(size_t)i * 8] = vl;
    }
}

// K_vt: xv[f][k][d] f32 -> vt[f][d][k] f16, 64x64 LDS-tiled transpose.
__global__ __launch_bounds__(256) void mta_vt_kernel(const float* __restrict__ xv,
                                                     unsigned short* __restrict__ vt) {
    const int kt = blockIdx.x, f = blockIdx.y;
    const int tid = threadIdx.x;
    __shared__ unsigned short lt[64][65];
#pragma unroll
    for (int i = 0; i < 16; ++i) {
        int idx = tid + i * 256;
        int r = idx >> 6, c = idx & 63;
        lt[r][c] = f2h(xv[((size_t)f * S + kt * 64 + r) * D + c]);
    }
    __syncthreads();
#pragma unroll
    for (int i = 0; i < 16; ++i) {
        int idx = tid + i * 256;
        int d = idx >> 6, k = idx & 63;
        vt[((size_t)f * D + d) * S + kt * 64 + k] = lt[k][d];
    }
}

// ---------------------------------------------------------------------------
// K_gemm: raw scores per head, 64q x 64k tile, split-bf16 (hi*hi+hi*lo+lo*hi),
// causal-zeroed, written f16 to R[h][lrow][k]. lrow 0 == global row qs-64.
__global__ __launch_bounds__(256) void mta_gemm_kernel(
        const unsigned short* __restrict__ qhi, const unsigned short* __restrict__ qlo,
        const unsigned short* __restrict__ khi, const unsigned short* __restrict__ klo,
        unsigned short* __restrict__ R, int qs, int SQ) {
    const int kt = blockIdx.x, qt = blockIdx.y, h = blockIdx.z;
    const int q0 = qs - 64 + qt * 64;
    const int k0 = kt * 64;
    if (k0 > q0 + 63) return;
    const int tid = threadIdx.x;
    const int SQ64 = SQ + 64;

    __shared__ unsigned short Qs[2][64][72];   // [hi/lo][row][col]
    __shared__ unsigned short Ks[2][64][72];
    __shared__ unsigned short Ro[64][72];

    {   // stage: each thread 16 cols of one row for Q and K (hi+lo)
        int r = tid >> 2, d = (tid & 3) * 16;
        int gq = q0 + r;
        uint4 z = {0u, 0u, 0u, 0u};
        uint4 a0 = z, a1 = z, b0 = z, b1 = z;
        if (gq >= 0) {
            size_t off = ((size_t)h * S + gq) * D + d;
            a0 = *(const uint4*)&qhi[off]; a1 = *(const uint4*)&qhi[off + 8];
            b0 = *(const uint4*)&qlo[off]; b1 = *(const uint4*)&qlo[off + 8];
        }
        *(uint4*)&Qs[0][r][d] = a0; *(uint4*)&Qs[0][r][d + 8] = a1;
        *(uint4*)&Qs[1][r][d] = b0; *(uint4*)&Qs[1][r][d + 8] = b1;
        size_t offk = ((size_t)h * S + (k0 + r)) * D + d;
        uint4 c0 = *(const uint4*)&khi[offk];
        uint4 c1 = *(const uint4*)&khi[offk + 8];
        uint4 d0 = *(const uint4*)&klo[offk];
        uint4 d1 = *(const uint4*)&klo[offk + 8];
        *(uint4*)&Ks[0][r][d] = c0; *(uint4*)&Ks[0][r][d + 8] = c1;
        *(uint4*)&Ks[1][r][d] = d0; *(uint4*)&Ks[1][r][d + 8] = d1;
    }
    __syncthreads();

    const int w = tid >> 6, lane = tid & 63;
    const int wr = w >> 1, wc = w & 1;
    const int lr = lane & 15, lk = lane >> 4;

    f32x4 acc[2][2];
#pragma unroll
    for (int mi = 0; mi < 2; ++mi)
#pragma unroll
        for (int ni = 0; ni < 2; ++ni) acc[mi][ni] = (f32x4){0.f, 0.f, 0.f, 0.f};

#pragma unroll
    for (int ks = 0; ks < 2; ++ks) {
        int db = ks * 32 + lk * 8;
#pragma unroll
        for (int mi = 0; mi < 2; ++mi) {
            bf16x8 ah = *(const bf16x8*)&Qs[0][wr * 32 + mi * 16 + lr][db];
            bf16x8 al = *(const bf16x8*)&Qs[1][wr * 32 + mi * 16 + lr][db];
#pragma unroll
            for (int ni = 0; ni < 2; ++ni) {
                bf16x8 bh = *(const bf16x8*)&Ks[0][wc * 32 + ni * 16 + lr][db];
                bf16x8 bl = *(const bf16x8*)&Ks[1][wc * 32 + ni * 16 + lr][db];
                acc[mi][ni] = __builtin_amdgcn_mfma_f32_16x16x32_bf16(ah, bh, acc[mi][ni], 0, 0, 0);
                acc[mi][ni] = __builtin_amdgcn_mfma_f32_16x16x32_bf16(ah, bl, acc[mi][ni], 0, 0, 0);
                acc[mi][ni] = __builtin_amdgcn_mfma_f32_16x16x32_bf16(al, bh, acc[mi][ni], 0, 0, 0);
            }
        }
    }

    // causal-zero + pack to Ro (f16)
#pragma unroll
    for (int mi = 0; mi < 2; ++mi)
#pragma unroll
        for (int ni = 0; ni < 2; ++ni)
#pragma unroll
            for (int i = 0; i < 4; ++i) {
                int row = wr * 32 + mi * 16 + lk * 4 + i;  // C/D: col=lane&15, row=(lane>>4)*4+i
                int col = wc * 32 + ni * 16 + lr;
                int gq = q0 + row, gk = k0 + col;
                Ro[row][col] = f2h((gk <= gq) ? acc[mi][ni][i] : 0.f);
            }
    __syncthreads();

    // coalesced global write: 64 rows x 128B
#pragma unroll
    for (int ii = 0; ii < 2; ++ii) {
        int idx = tid + ii * 256;
        int row = idx >> 3, c8 = (idx & 7) * 8;
        int lrow = qt * 64 + row;
        *(uint4*)&R[((size_t)h * SQ64 + lrow) * S + k0 + c8] = *(const uint4*)&Ro[row][c8];
    }
}

// ---------------------------------------------------------------------------
// K_convmix: 6x11 causal conv over R + w_psm head mix -> sc (f16 mixed scores).
// 16q x 64k tile per block; double-buffered LDS staging, 1 barrier/head.
__global__ __launch_bounds__(256) void mta_convmix_kernel(
        const unsigned short* __restrict__ R,
        const float* __restrict__ w_pre, const float* __restrict__ w_psm,
        unsigned short* __restrict__ sc, int qs, int SQ) {
    const int kc = blockIdx.x, qt = blockIdx.y;
    const int q0 = qs - 16 + qt * 16;   // qt==0 is the stripe halo tile
    const int k0 = kc * 64;
    if (k0 > q0 + 15) return;
    const int tid = threadIdx.x;
    const int SQ64 = SQ + 64;

    __shared__ float raw_s[2][21][76];
    __shared__ float wpre_s[16 * 66];
    __shared__ float wpsm_s[256];
    for (int i = tid; i < 16 * 66; i += 256) wpre_s[i] = w_pre[i];
    wpsm_s[tid] = w_psm[tid];

    const int ql = tid & 15, kgrp = tid >> 4, kb = kgrp * 4;
    const int q = q0 + ql;

    float acc0[16], acc1[16], acc2[16], acc3[16];
#pragma unroll
    for (int g = 0; g < 16; ++g) { acc0[g] = 0.f; acc1[g] = 0.f; acc2[g] = 0.f; acc3[g] = 0.f; }

#define STAGEC(hh, bb) do { \
        for (int i_ = tid; i_ < 21 * 37; i_ += 256) { \
            int r_ = i_ / 37, c2_ = (i_ % 37) * 2; \
            int qp_ = q0 - 5 + r_; \
            int kp_ = k0 - 10 + c2_; \
            float f0_ = 0.f, f1_ = 0.f; \
            if (qp_ >= 0) { \
                const unsigned short* rp_ = &R[((size_t)(hh) * SQ64 + (qp_ - (qs - 64))) * S]; \
                if (kp_ >= 0 && kp_ <= qp_)         f0_ = h2f(rp_[kp_]); \
                if (kp_ + 1 >= 0 && kp_ + 1 <= qp_) f1_ = h2f(rp_[kp_ + 1]); \
            } \
            raw_s[bb][r_][c2_] = f0_; raw_s[bb][r_][c2_ + 1] = f1_; \
        } \
    } while (0)

#define CONVC(hh, bb) do { \
        float c0_ = 0.f, c1_ = 0.f, c2_ = 0.f, c3_ = 0.f; \
        _Pragma("unroll") \
        for (int i2_ = 0; i2_ < 6; ++i2_) { \
            const float* rp_ = &raw_s[bb][ql + i2_][kb]; \
            float v_[14]; \
            _Pragma("unroll") \
            for (int j_ = 0; j_ < 7; ++j_) { \
                float2 t_ = *(const float2*)(rp_ + 2 * j_); \
                v_[2 * j_] = t_.x; v_[2 * j_ + 1] = t_.y; } \
            const float* wp_ = &wpre_s[(hh) * 66 + i2_ * 11]; \
            _Pragma("unroll") \
            for (int j_ = 0; j_ < 11; ++j_) { \
                float w_ = wp_[j_]; \
                c0_ += w_ * v_[j_];     c1_ += w_ * v_[j_ + 1]; \
                c2_ += w_ * v_[j_ + 2]; c3_ += w_ * v_[j_ + 3]; } \
        } \
        _Pragma("unroll") \
        for (int g_ = 0; g_ < 16; ++g_) { \
            float wg_ = wpsm_s[g_ * 16 + (hh)]; \
            acc0[g_] += wg_ * c0_; acc1[g_] += wg_ * c1_; \
            acc2[g_] += wg_ * c2_; acc3[g_] += wg_ * c3_; } \
    } while (0)

    STAGEC(0, 0);
    __syncthreads();
    for (int h = 0; h < 16; ++h) {
        if (h < 15) STAGEC(h + 1, (h + 1) & 1);
        CONVC(h, h & 1);
        __syncthreads();
    }
#undef STAGEC
#undef CONVC

    // write mixed scores f16 (0 above diagonal)
    const int srow = qt * 16 + ql;      // = q - (qs-16)
    const int kk = k0 + kb;
#pragma unroll
    for (int g = 0; g < 16; ++g) {
        unsigned int p0 = pack2h((kk     <= q) ? acc0[g] : 0.f,
                                 (kk + 1 <= q) ? acc1[g] : 0.f);
        unsigned int p1 = pack2h((kk + 2 <= q) ? acc2[g] : 0.f,
                                 (kk + 3 <= q) ? acc3[g] : 0.f);
        unsigned short* sp = &sc[((size_t)(g * (SQ + 16) + srow)) * S + kk];
        *(unsigned int*)sp = p0;
        *(unsigned int*)(sp + 2) = p1;
    }
}

// ---------------------------------------------------------------------------
// Stats: per (g,q) row of the stripe, m = max, l = sum exp(x-m) over k<=q.
__global__ __launch_bounds__(256) void mta_rowstats_kernel(
        const unsigned short* __restrict__ sc,
        float* __restrict__ mrow, float* __restrict__ rlrow, int qs, int SQ) {
    int row = blockIdx.x * 4 + (threadIdx.x >> 6);
    int lane = threadIdx.x & 63;
    int g = row / SQ, qq = row % SQ;
    int q = qs + qq;
    const unsigned short* rp = sc + ((size_t)(g * (SQ + 16) + qq + 16)) * S;

    float v[32];
#pragma unroll
    for (int it = 0; it < 4; ++it) {
        int kbase = it * 512 + lane * 8;
        if (it * 512 <= q) {
            uint4 u = *(const uint4*)&rp[kbase];
            unsigned int ws[4] = {u.x, u.y, u.z, u.w};
#pragma unroll
            for (int j = 0; j < 4; ++j) {
                float x0 = h2f((unsigned short)(ws[j] & 0xffff));
                float x1 = h2f((unsigned short)(ws[j] >> 16));
                v[it * 8 + 2 * j]     = (kbase + 2 * j     <= q) ? x0 : -INFINITY;
                v[it * 8 + 2 * j + 1] = (kbase + 2 * j + 1 <= q) ? x1 : -INFINITY;
            }
        } else {
#pragma unroll
            for (int j = 0; j < 8; ++j) v[it * 8 + j] = -INFINITY;
        }
    }
    float m = -INFINITY;
#pragma unroll
    for (int j = 0; j < 32; ++j) m = fmaxf(m, v[j]);
#pragma unroll
    for (int off = 1; off < 64; off <<= 1) m = fmaxf(m, __shfl_xor(m, off));
    float l = 0.f;
#pragma unroll
    for (int j = 0; j < 32; ++j) l += __expf(v[j] - m);
#pragma unroll
    for (int off = 1; off < 64; off <<= 1) l += __shfl_xor(l, off);
    if (lane == 0) { mrow[g * S + q] = m; rlrow[g * S + q] = 1.f / l; }
}

// ---------------------------------------------------------------------------
// Pass 2: probs = exp(sc - m)/l, 3x3 causal conv, w_posm mix, MFMA PV.
__global__ __launch_bounds__(256) void mta_out2_kernel(
        const unsigned short* __restrict__ sc,
        const float* __restrict__ mrow, const float* __restrict__ rlrow,
        const unsigned short* __restrict__ vt,
        const float* __restrict__ w_post, const float* __restrict__ w_posm,
        float* __restrict__ out, int qs, int SQ) {
    const int qt = blockIdx.x, kc = blockIdx.y;
    const int q0 = qs + qt * 16;
    const int kstart = kc * CH;
    if (kstart > q0 + 15) return;
    const int kend = min(kstart + CH, q0 + 16);
    const int tid = threadIdx.x;

    __shared__ unsigned short ps[16][18][36];
    __shared__ unsigned short pm2[16][16][40];
    __shared__ float mst[16][18], rst[16][18];
    __shared__ float wpost_s[144], wposm_s[256];

    wposm_s[tid] = w_posm[tid];
    if (tid < 144) wpost_s[tid] = w_post[tid];
    for (int i = tid; i < 288; i += 256) {
        int g = i / 18, r = i % 18;
        int qp = q0 - 2 + r;
        if (qp >= 0) { mst[g][r] = mrow[g * S + qp]; rst[g][r] = rlrow[g * S + qp]; }
        else         { mst[g][r] = 0.f; rst[g][r] = 0.f; }
    }

    const int ql = tid >> 4, kb = (tid & 15) * 2;
    const int wv = tid >> 6, lane = tid & 63;
    const int lr = lane & 15, lk = lane >> 4;

    f32x4 acc[4][4];
#pragma unroll
    for (int a = 0; a < 4; ++a)
#pragma unroll
        for (int b = 0; b < 4; ++b) acc[a][b] = (f32x4){0.f, 0.f, 0.f, 0.f};

    __syncthreads();

    for (int k0 = kstart; k0 < kend; k0 += 32) {
        for (int i = tid; i < 4896; i += 256) {
            int g = i / 306, rem = i % 306;
            int r = rem / 17, c2 = (rem % 17) * 2;
            int qp = q0 - 2 + r;
            int kp = k0 - 2 + c2;
            float p0 = 0.f, p1 = 0.f;
            if (qp >= 0 && kp >= 0) {
                unsigned int u = *(const unsigned int*)
                    &sc[((size_t)(g * (SQ + 16) + qp - (qs - 16))) * S + kp];
                float mm = mst[g][r], rr = rst[g][r];
                if (kp <= qp)     p0 = __expf(h2f((unsigned short)(u & 0xffff)) - mm) * rr;
                if (kp + 1 <= qp) p1 = __expf(h2f((unsigned short)(u >> 16)) - mm) * rr;
            }
            *(unsigned int*)&ps[g][r][c2] = pack2h(p0, p1);
        }
        __syncthreads();

        {
            float cg0[16], cg1[16];
#pragma unroll
            for (int g = 0; g < 16; ++g) {
                float c0 = 0.f, c1 = 0.f;
#pragma unroll
                for (int i2 = 0; i2 < 3; ++i2) {
                    unsigned int u0 = *(const unsigned int*)&ps[g][ql + i2][kb];
                    unsigned int u1 = *(const unsigned int*)&ps[g][ql + i2][kb + 2];
                    float v0 = h2f((unsigned short)(u0 & 0xffff));
                    float v1 = h2f((unsigned short)(u0 >> 16));
                    float v2 = h2f((unsigned short)(u1 & 0xffff));
                    float v3 = h2f((unsigned short)(u1 >> 16));
                    const float* wp = &wpost_s[g * 9 + i2 * 3];
                    c0 += wp[0] * v0 + wp[1] * v1 + wp[2] * v2;
                    c1 += wp[0] * v1 + wp[1] * v2 + wp[2] * v3;
                }
                cg0[g] = c0; cg1[g] = c1;
            }
            int q = q0 + ql, k = k0 + kb;
            bool val0 = (k <= q) && (k < kend);
            bool val1 = (k + 1 <= q) && (k + 1 < kend);
#pragma unroll
            for (int ff = 0; ff < 16; ++ff) {
                float s0 = 0.f, s1 = 0.f;
#pragma unroll
                for (int g = 0; g < 16; ++g) {
                    float w = wposm_s[ff * 16 + g];
                    s0 += w * cg0[g]; s1 += w * cg1[g];
                }
                *(unsigned int*)&pm2[ff][ql][kb] = pack2h(val0 ? s0 : 0.f, val1 ? s1 : 0.f);
            }
        }
        __syncthreads();

#pragma unroll
        for (int hh = 0; hh < 4; ++hh) {
            int f = wv * 4 + hh;
            f16x8 a = *(const f16x8*)&pm2[f][lr][lk * 8];
#pragma unroll
            for (int tc = 0; tc < 4; ++tc) {
                uint4 braw = *(const uint4*)
                    &vt[((size_t)(f * D + tc * 16 + lr)) * S + k0 + lk * 8];
                f16x8 b;
                __builtin_memcpy(&b, &braw, 16);
                acc[hh][tc] = __builtin_amdgcn_mfma_f32_16x16x32_f16(a, b, acc[hh][tc], 0, 0, 0);
            }
        }
    }

#pragma unroll
    for (int hh = 0; hh < 4; ++hh) {
        int f = wv * 4 + hh;
#pragma unroll
        for (int tc = 0; tc < 4; ++tc) {
#pragma unroll
            for (int i = 0; i < 4; ++i) {
                int q = q0 + lk * 4 + i;
                int d = tc * 16 + lr;
                atomicAdd(&out[((size_t)q * H + f) * D + d], acc[hh][tc][i]);
            }
        }
    }
}

// ===========================================================================
// Fallback path (round-2 kernels, verbatim): used when ws_size is too small.
// ===========================================================================
__global__ __launch_bounds__(256) void fb_stats_kernel(
        const float* __restrict__ xq, const float* __restrict__ xk,
        const float* __restrict__ w_pre, const float* __restrict__ w_psm,
        float* __restrict__ mpart, float* __restrict__ lpart) {
    const int kc = blockIdx.x, qt = blockIdx.y;
    const int q0 = qt * 16;
    const int kstart = kc * CH;
    if (kstart > q0 + 15) return;
    const int kend = min(kstart + CH, q0 + 16);
    const int tid = threadIdx.x;

    __shared__ unsigned short Qs[2][32][72];
    __shared__ unsigned short Ks[2][48][72];
    __shared__ float raws[32][50];
    __shared__ float wpre_s[16 * 66];
    __shared__ float wpsm_s[256];

    for (int i = tid; i < 16 * 66; i += 256) wpre_s[i] = w_pre[i];
    wpsm_s[tid] = w_psm[tid];

    const int ql = tid >> 4;
    const int kb = (tid & 15) * 2;
    const int q = q0 + ql;

    float mreg[16], lreg[16];
#pragma unroll
    for (int g = 0; g < 16; ++g) { mreg[g] = -INFINITY; lreg[g] = 0.f; }

    for (int k0 = kstart; k0 < kend; k0 += 32) {
        float acc0[16], acc1[16];
#pragma unroll
        for (int g = 0; g < 16; ++g) { acc0[g] = 0.f; acc1[g] = 0.f; }

        for (int h = 0; h < H; ++h) {
            {
                int r = tid >> 3, d = (tid & 7) * 8;
                int qp = q0 - 5 + r;
                float4 a = {0,0,0,0}, b = {0,0,0,0};
                if (r < 21 && qp >= 0) {
                    const float* p = &xq[(h * S + qp) * D + d];
                    a = *(const float4*)p; b = *(const float4*)(p + 4);
                }
                uint4 vh, vl; stage_hilo(a, b, &vh, &vl);
                *(uint4*)&Qs[0][r][d] = vh;
                *(uint4*)&Qs[1][r][d] = vl;
            }
            for (int i = tid; i < 384; i += 256) {
                int r = i >> 3, d = (i & 7) * 8;
                int kp = k0 - 10 + r;
                float4 a = {0,0,0,0}, b = {0,0,0,0};
                if (r < 42 && kp >= 0) {
                    const float* p = &xk[(h * S + kp) * D + d];
                    a = *(const float4*)p; b = *(const float4*)(p + 4);
                }
                uint4 vh, vl; stage_hilo(a, b, &vh, &vl);
                *(uint4*)&Ks[0][r][d] = vh;
                *(uint4*)&Ks[1][r][d] = vl;
            }
            __syncthreads();
            {
                int w = tid >> 6, l = tid & 63;
                int lr = l & 15, lk = l >> 4;
                for (int t = w; t < 6; t += 4) {
                    int tr = t / 3, tc = t % 3;
                    f32x4 acc = {0.f, 0.f, 0.f, 0.f};
#pragma unroll
                    for (int ks = 0; ks < 2; ++ks) {
                        int db = ks * 32 + lk * 8;
                        bf16x8 ah = *(const bf16x8*)&Qs[0][tr * 16 + lr][db];
                        bf16x8 al = *(const bf16x8*)&Qs[1][tr * 16 + lr][db];
                        bf16x8 bh = *(const bf16x8*)&Ks[0][tc * 16 + lr][db];
                        bf16x8 bl = *(const bf16x8*)&Ks[1][tc * 16 + lr][db];
                        acc = __builtin_amdgcn_mfma_f32_16x16x32_bf16(ah, bh, acc, 0, 0, 0);
                        acc = __builtin_amdgcn_mfma_f32_16x16x32_bf16(ah, bl, acc, 0, 0, 0);
                        acc = __builtin_amdgcn_mfma_f32_16x16x32_bf16(al, bh, acc, 0, 0, 0);
                    }
#pragma unroll
                    for (int i = 0; i < 4; ++i) {
                        int row = tr * 16 + lk * 4 + i;
                        int col = tc * 16 + lr;
                        int qp = q0 - 5 + row, kp = k0 - 10 + col;
                        raws[row][col] = (kp >= 0 && kp <= qp) ? acc[i] * SCALEQK : 0.f;
                    }
                }
            }
            __syncthreads();
            {
                float c0 = 0.f, c1 = 0.f;
#pragma unroll
                for (int i2 = 0; i2 < 6; ++i2) {
                    const float* rp = &raws[ql + i2][kb];
                    float v[12];
#pragma unroll
                    for (int j = 0; j < 6; ++j) {
                        float2 t = *(const float2*)(rp + 2 * j);
                        v[2 * j] = t.x; v[2 * j + 1] = t.y;
                    }
                    const float* wp = &wpre_s[h * 66 + i2 * 11];
#pragma unroll
                    for (int j = 0; j < 11; ++j) { c0 += wp[j] * v[j]; c1 += wp[j] * v[j + 1]; }
                }
#pragma unroll
                for (int g = 0; g < 16; ++g) {
                    float wg = wpsm_s[g * 16 + h];
                    acc0[g] += wg * c0; acc1[g] += wg * c1;
                }
            }
        }
        int kk = k0 + kb;
#pragma unroll
        for (int g = 0; g < 16; ++g) {
            if (kk <= q)     online_upd(mreg[g], lreg[g], acc0[g]);
            if (kk + 1 <= q) online_upd(mreg[g], lreg[g], acc1[g]);
        }
    }
#pragma unroll
    for (int g = 0; g < 16; ++g) {
        float m = mreg[g], l = lreg[g];
#pragma unroll
        for (int off = 1; off < 16; off <<= 1) {
            float m2 = __shfl_xor(m, off);
            float l2 = __shfl_xor(l, off);
            float nm = fmaxf(m, m2);
            float t1 = (l  > 0.f) ? l  * __expf(m  - nm) : 0.f;
            float t2 = (l2 > 0.f) ? l2 * __expf(m2 - nm) : 0.f;
            m = nm; l = t1 + t2;
        }
        if ((tid & 15) == 0) {
            mpart[((size_t)kc * H + g) * S + q] = m;
            lpart[((size_t)kc * H + g) * S + q] = l;
        }
    }
}

__global__ __launch_bounds__(256) void fb_reduce_kernel(
        const float* __restrict__ mpart, const float* __restrict__ lpart,
        float* __restrict__ mrow, float* __restrict__ rlrow) {
    int r = blockIdx.x * 256 + threadIdx.x;
    if (r >= H * S) return;
    int q = r & (S - 1);
    int nkc = (q >> 8) + 1;
    float m = -INFINITY;
    for (int kc = 0; kc < nkc; ++kc) m = fmaxf(m, mpart[(size_t)kc * H * S + r]);
    float l = 0.f;
    for (int kc = 0; kc < nkc; ++kc) {
        float li = lpart[(size_t)kc * H * S + r];
        float mi = mpart[(size_t)kc * H * S + r];
        if (li > 0.f) l += li * __expf(mi - m);
    }
    mrow[r] = m;
    rlrow[r] = 1.f / l;
}

__global__ __launch_bounds__(256) void fb_out_kernel(
        const float* __restrict__ xq, const float* __restrict__ xk,
        const float* __restrict__ xv,
        const float* __restrict__ w_pre, const float* __restrict__ w_psm,
        const float* __restrict__ w_post, const float* __restrict__ w_posm,
        const float* __restrict__ mrow, const float* __restrict__ rlrow,
        float* __restrict__ out) {
    const int qt = blockIdx.x, kc = blockIdx.y;
    const int q0 = qt * 8;
    const int kstart = kc * CH;
    if (kstart > q0 + 7) return;
    const int kend = min(kstart + CH, q0 + 8);
    const int tid = threadIdx.x;

    __shared__ unsigned short Qs[2][16][72];
    __shared__ unsigned short Ks[2][48][72];
    __shared__ float raws[16][50];
    __shared__ float ps[8][10][35];
    __shared__ float m2s[16][8][33];
    __shared__ float mst[16][10], rst[16][10];
    __shared__ float wpre_s[16 * 66], wpsm_s[256], wpost_s[144], wposm_s[256];

    for (int i = tid; i < 16 * 66; i += 256) wpre_s[i] = w_pre[i];
    wpsm_s[tid] = w_psm[tid];
    wposm_s[tid] = w_posm[tid];
    if (tid < 144) wpost_s[tid] = w_post[tid];
    for (int i = tid; i < 160; i += 256) {
        int g = i / 10, r = i % 10;
        int qp = q0 - 2 + r;
        if (qp >= 0) { mst[g][r] = mrow[g * S + qp]; rst[g][r] = rlrow[g * S + qp]; }
        else         { mst[g][r] = 0.f; rst[g][r] = 0.f; }
    }

    const int f = tid >> 4, qloc = (tid >> 1) & 7, dh = tid & 1;
    const int cr = tid / 17, cc = (tid % 17) * 2;
    const bool cvalid = tid < 170;
    const int ql2 = tid >> 5, kl = tid & 31;

    float oacc[32];
#pragma unroll
    for (int i = 0; i < 32; ++i) oacc[i] = 0.f;

    for (int k0 = kstart; k0 < kend; k0 += 32) {
        float a0[16], a1[16];
#pragma unroll
        for (int g = 0; g < 16; ++g) { a0[g] = 0.f; a1[g] = 0.f; }

        for (int h = 0; h < H; ++h) {
            if (tid < 128) {
                int r = tid >> 3, d = (tid & 7) * 8;
                int qp = q0 - 7 + r;
                float4 a = {0,0,0,0}, b = {0,0,0,0};
                if (qp >= 0 && qp < S) {
                    const float* p = &xq[(h * S + qp) * D + d];
                    a = *(const float4*)p; b = *(const float4*)(p + 4);
                }
                uint4 vh, vl; stage_hilo(a, b, &vh, &vl);
                *(uint4*)&Qs[0][r][d] = vh;
                *(uint4*)&Qs[1][r][d] = vl;
            }
            for (int i = tid; i < 384; i += 256) {
                int r = i >> 3, d = (i & 7) * 8;
                int kp = k0 - 12 + r;
                float4 a = {0,0,0,0}, b = {0,0,0,0};
                if (kp >= 0 && kp < S) {
                    const float* p = &xk[(h * S + kp) * D + d];
                    a = *(const float4*)p; b = *(const float4*)(p + 4);
                }
                uint4 vh, vl; stage_hilo(a, b, &vh, &vl);
                *(uint4*)&Ks[0][r][d] = vh;
                *(uint4*)&Ks[1][r][d] = vl;
            }
            __syncthreads();
            {
                int w = tid >> 6, l = tid & 63;
                int lr = l & 15, lk = l >> 4;
                if (w < 3) {
                    int tc = w;
                    f32x4 acc = {0.f, 0.f, 0.f, 0.f};
#pragma unroll
                    for (int ks = 0; ks < 2; ++ks) {
                        int db = ks * 32 + lk * 8;
                        bf16x8 ah = *(const bf16x8*)&Qs[0][lr][db];
                        bf16x8 al = *(const bf16x8*)&Qs[1][lr][db];
                        bf16x8 bh = *(const bf16x8*)&Ks[0][tc * 16 + lr][db];
                        bf16x8 bl = *(const bf16x8*)&Ks[1][tc * 16 + lr][db];
                        acc = __builtin_amdgcn_mfma_f32_16x16x32_bf16(ah, bh, acc, 0, 0, 0);
                        acc = __builtin_amdgcn_mfma_f32_16x16x32_bf16(ah, bl, acc, 0, 0, 0);
                        acc = __builtin_amdgcn_mfma_f32_16x16x32_bf16(al, bh, acc, 0, 0, 0);
                    }
#pragma unroll
                    for (int i = 0; i < 4; ++i) {
                        int row = lk * 4 + i, col = tc * 16 + lr;
                        int qp = q0 - 7 + row, kp = k0 - 12 + col;
                        raws[row][col] = (kp >= 0 && kp <= qp) ? acc[i] * SCALEQK : 0.f;
                    }
                }
            }
            __syncthreads();
            if (cvalid) {
                float c0 = 0.f, c1 = 0.f;
#pragma unroll
                for (int i2 = 0; i2 < 6; ++i2) {
                    const float* rp = &raws[cr + i2][cc];
                    float v[12];
#pragma unroll
                    for (int j = 0; j < 6; ++j) {
                        float2 t = *(const float2*)(rp + 2 * j);
                        v[2 * j] = t.x; v[2 * j + 1] = t.y;
                    }
                    const float* wp = &wpre_s[h * 66 + i2 * 11];
#pragma unroll
                    for (int j = 0; j < 11; ++j) { c0 += wp[j] * v[j]; c1 += wp[j] * v[j + 1]; }
                }
#pragma unroll
                for (int g = 0; g < 16; ++g) {
                    float wg = wpsm_s[g * 16 + h];
                    a0[g] += wg * c0; a1[g] += wg * c1;
                }
            }
        }

        float m2f[16];
#pragma unroll
        for (int i = 0; i < 16; ++i) m2f[i] = 0.f;

        for (int half = 0; half < 2; ++half) {
            if (cvalid) {
                int qp = q0 - 2 + cr;
                int kp0 = k0 - 2 + cc, kp1 = kp0 + 1;
#pragma unroll
                for (int g8 = 0; g8 < 8; ++g8) {
                    int g = half * 8 + g8;
                    float p0 = 0.f, p1 = 0.f;
                    if (qp >= 0) {
                        float mm = mst[g][cr], rr = rst[g][cr];
                        if (kp0 >= 0 && kp0 <= qp) p0 = __expf(a0[g] - mm) * rr;
                        if (kp1 >= 0 && kp1 <= qp) p1 = __expf(a1[g] - mm) * rr;
                    }
                    ps[g8][cr][cc] = p0;
                    ps[g8][cr][cc + 1] = p1;
                }
            }
            __syncthreads();
            {
                float cg[8];
#pragma unroll
                for (int g8 = 0; g8 < 8; ++g8) {
                    float c = 0.f;
#pragma unroll
                    for (int i2 = 0; i2 < 3; ++i2)
#pragma unroll
                        for (int j2 = 0; j2 < 3; ++j2)
                            c += wpost_s[(half * 8 + g8) * 9 + i2 * 3 + j2] * ps[g8][ql2 + i2][kl + j2];
                    cg[g8] = c;
                }
#pragma unroll
                for (int ff = 0; ff < 16; ++ff) {
                    float s = 0.f;
#pragma unroll
                    for (int g8 = 0; g8 < 8; ++g8) s += wposm_s[ff * 16 + half * 8 + g8] * cg[g8];
                    m2f[ff] += s;
                }
            }
            if (half == 0) __syncthreads();
        }
        {
            int q = q0 + ql2, k = k0 + kl;
            bool valid = (k <= q) && (k < kend);
#pragma unroll
            for (int ff = 0; ff < 16; ++ff) m2s[ff][ql2][kl] = valid ? m2f[ff] : 0.f;
        }
        __syncthreads();
        for (int kl2 = 0; kl2 < 32; ++kl2) {
            int k = k0 + kl2;
            if (k >= kend) break;
            float s = m2s[f][qloc][kl2];
            if (s != 0.f) {
                const float* vp = &xv[(f * S + k) * D + dh * 32];
#pragma unroll
                for (int d4 = 0; d4 < 8; ++d4) {
                    float4 v = *(const float4*)(vp + d4 * 4);
                    oacc[d4 * 4 + 0] += s * v.x;
                    oacc[d4 * 4 + 1] += s * v.y;
                    oacc[d4 * 4 + 2] += s * v.z;
                    oacc[d4 * 4 + 3] += s * v.w;
                }
            }
        }
        __syncthreads();
    }

    int q = q0 + qloc;
    float* op = out + ((size_t)q * H + f) * D + dh * 32;
#pragma unroll
    for (int i = 0; i < 32; ++i) atomicAdd(op + i, oacc[i]);
}

// ===========================================================================
extern "C" void kernel_launch(void* const* d_in, const int* in_sizes, int n_in,
                              void* d_out, int out_size, void* d_ws, size_t ws_size,
                              hipStream_t stream) {
    const float* xq     = (const float*)d_in[0];
    const float* xk     = (const float*)d_in[1];
    const float* xv     = (const float*)d_in[2];
    const float* w_pre  = (const float*)d_in[4];
    const float* w_post = (const float*)d_in[5];
    const float* w_psm  = (const float*)d_in[6];
    const float* w_posm = (const float*)d_in[7];
    float* out = (float*)d_out;

    hipMemsetAsync(d_out, 0, sizeof(float) * (size_t)out_size, stream);

    const size_t qkb   = (size_t)H * S * D * 2;   // 4 MiB per hi/lo array
    const size_t vtb   = (size_t)H * D * S * 2;   // 4 MiB
    const size_t statb = (size_t)H * S * 4;       // 128 KiB
    const size_t base  = 4 * qkb + vtb + 2 * statb;

    int SQ = 0;
    const int cands[5] = {2048, 1024, 512, 256, 128};
    for (int c = 0; c < 5; ++c) {
        size_t rb  = (size_t)H * (cands[c] + 64) * S * 2;
        size_t scb = (size_t)H * (cands[c] + 16) * S * 2;
        if (base + rb + scb <= ws_size) { SQ = cands[c]; break; }
    }

    if (SQ == 0) {
        float* mpart = (float*)d_ws;
        float* lpart = mpart + (size_t)8 * H * S;
        float* mrow  = lpart + (size_t)8 * H * S;
        float* rlrow = mrow + (size_t)H * S;
        dim3 g1(8, 128);
        fb_stats_kernel<<<g1, 256, 0, stream>>>(xq, xk, w_pre, w_psm, mpart, lpart);
        fb_reduce_kernel<<<128, 256, 0, stream>>>(mpart, lpart, mrow, rlrow);
        dim3 g2(256, 8);
        fb_out_kernel<<<g2, 256, 0, stream>>>(xq, xk, xv, w_pre, w_psm, w_post, w_posm,
                                              mrow, rlrow, out);
        return;
    }

    char* p = (char*)d_ws;
    unsigned short* qhi = (unsigned short*)p;            p += qkb;
    unsigned short* qlo = (unsigned short*)p;            p += qkb;
    unsigned short* khi = (unsigned short*)p;            p += qkb;
    unsigned short* klo = (unsigned short*)p;            p += qkb;
    unsigned short* vt  = (unsigned short*)p;            p += vtb;
    float* mrow  = (float*)p;                            p += statb;
    float* rlrow = (float*)p;                            p += statb;
    unsigned short* Rbuf = (unsigned short*)p;           p += (size_t)H * (SQ + 64) * S * 2;
    unsigned short* sc   = (unsigned short*)p;

    const int n8 = H * S * D / 8;
    mta_cvt_kernel<<<512, 256, 0, stream>>>(xq, qhi, qlo, SCALEQK, n8);
    mta_cvt_kernel<<<512, 256, 0, stream>>>(xk, khi, klo, 1.0f, n8);
    dim3 gv(S / 64, H);
    mta_vt_kernel<<<gv, 256, 0, stream>>>(xv, vt);

    for (int qs = 0; qs < S; qs += SQ) {
        dim3 gg(S / 64, SQ / 64 + 1, H);
        mta_gemm_kernel<<<gg, 256, 0, stream>>>(qhi, qlo, khi, klo, Rbuf, qs, SQ);
        dim3 gc(S / 64, SQ / 16 + 1);
        mta_convmix_kernel<<<gc, 256, 0, stream>>>(Rbuf, w_pre, w_psm, sc, qs, SQ);
        mta_rowstats_kernel<<<4 * SQ, 256, 0, stream>>>(sc, mrow, rlrow, qs, SQ);
        dim3 g2(SQ / 16, 8);
        mta_out2_kernel<<<g2, 256, 0, stream>>>(sc, mrow, rlrow, vt, w_post, w_posm,
                                                out, qs, SQ);
    }
}